// Round 7
// baseline (289.023 us; speedup 1.0000x reference)
//
#include <hip/hip_runtime.h>
#include <stdint.h>

#define BATCH 8
#define SEQ   1025
#define HDIM  1152
#define NH    12
#define DH    96
#define MROWS (BATCH*SEQ)   // 8200
#define N_QKV (3*HDIM)      // 3456
#define KD    HDIM          // 1152 (K of both GEMMs)
#define NTK   36            // K-tiles of 32

typedef __attribute__((ext_vector_type(8))) short short8;
typedef __attribute__((ext_vector_type(4))) short short4_;
typedef __attribute__((ext_vector_type(4))) float float4_;
typedef __attribute__((ext_vector_type(16))) float f32x16;

#define AS1 __attribute__((address_space(1)))
#define AS3 __attribute__((address_space(3)))
#define BARM() do { asm volatile("" ::: "memory"); __builtin_amdgcn_s_barrier(); asm volatile("" ::: "memory"); } while (0)

__device__ inline float bf2f(short s) {
  union { unsigned u; float f; } x; x.u = ((unsigned)(unsigned short)s) << 16; return x.f;
}
__device__ inline short f2bf(float f) {
  union { float f; unsigned u; } x; x.f = f;
  unsigned r = (x.u + 0x7fffu + ((x.u >> 16) & 1u)) >> 16;
  return (short)r;
}

// ---------------- converts ----------------
__global__ __launch_bounds__(256) void convx(const float* __restrict__ hs, short* __restrict__ X) {
  int i = blockIdx.x * 256 + threadIdx.x;  // exactly 2361600 threads
  float4_ v = ((const float4_*)hs)[i];
  short4_ o;
  o[0] = f2bf(v[0]); o[1] = f2bf(v[1]); o[2] = f2bf(v[2]); o[3] = f2bf(v[3]);
  ((short4_*)X)[i] = o;
}

// tiled transpose-cast: Wt[z*1152 + n][k] = W_z[k][n]
__global__ __launch_bounds__(256) void convw_t(const float* __restrict__ W0,
                                               const float* __restrict__ W1,
                                               const float* __restrict__ W2,
                                               short* __restrict__ Wt) {
  __shared__ float T[64][65];
  const int z = blockIdx.z;
  const float* W = z == 0 ? W0 : (z == 1 ? W1 : W2);
  const int n0 = blockIdx.x * 64, k0 = blockIdx.y * 64;
  const int tid = threadIdx.x;
  const int r = tid >> 2, cq = (tid & 3) * 16;
#pragma unroll
  for (int u = 0; u < 4; ++u) {
    float4_ v = *(const float4_*)&W[(long)(k0 + r) * HDIM + n0 + cq + u * 4];
    T[r][cq + u * 4 + 0] = v[0]; T[r][cq + u * 4 + 1] = v[1];
    T[r][cq + u * 4 + 2] = v[2]; T[r][cq + u * 4 + 3] = v[3];
  }
  __syncthreads();
  const int n = tid >> 2, kq = (tid & 3) * 16;
  short out[16];
#pragma unroll
  for (int u = 0; u < 16; ++u) out[u] = f2bf(T[kq + u][n]);
  short* dst = Wt + (long)(z * HDIM + n0 + n) * KD + k0 + kq;
  *(short8*)dst = *(short8*)&out[0];
  *(short8*)(dst + 8) = *(short8*)&out[8];
}

// ---------------- GEMM 256x256, 8-wave, QUAD-buffered BK=32, 3-deep prefetch ----------------
// LDS tile buffer = 128 lines x 128B; logical row r lives in line r>>1, half r&1.
// Swizzle (involution on the 3-bit within-line 16B-slot field, keyed on line):
//   phys_slot = ((r&1)*4 + lg) ^ ((r>>1)&7)
// Staging inverse on the per-lane SOURCE (global_load_lds writes linearly, Rule 21):
//   p -> wl=(p&7)^((p>>3)&7); row=(p>>3)*2+(wl>>2); kc=(wl&3)*8
// Pipeline: tile kt computes from buf kt&3 while tiles kt+1 (landed), kt+2, kt+3 (in flight)
// occupy the other 3 bufs. All 4 stage-loads for kt+3 issue at top of phase 0; steady-state
// wait is vmcnt(8) in phase 1 (tile kt+1's loads were issued ~6 phases earlier). Never 0
// mid-loop (T4); explicit 4->0 drain ladder in the last 3 tiles.
template<int OUTF32>
__global__ __launch_bounds__(512, 1) void gemm256(
    const short* __restrict__ A, const short* __restrict__ Bt,
    const float* __restrict__ b0, const float* __restrict__ b1, const float* __restrict__ b2,
    void* __restrict__ Cout, const int N, const int MT) {
  __shared__ alignas(16) short Lds[65536];  // 128KB: A bufs [4][8192], B bufs at 32768+[4][8192]
  const int tid = threadIdx.x;
  const int l = tid & 63, w = tid >> 6;
  const int lrow = l & 15, lg = l >> 4;
  const int wr = w >> 2, wc = w & 3;

  // bijective XCD swizzle (m204)
  const int nwg = gridDim.x;
  const int qq = nwg >> 3, r8 = nwg & 7;
  const int xcd = blockIdx.x & 7, loc = blockIdx.x >> 3;
  const int wg = (xcd < r8 ? xcd * (qq + 1) : r8 * (qq + 1) + (xcd - r8) * qq) + loc;
  const int mt = wg % MT, nt = wg / MT;
  const int m0 = mt * 256, n0 = nt * 256;

  // staging sources (inverse swizzle)
  const short* asrc[2]; const short* bsrc[2];
#pragma unroll
  for (int i = 0; i < 2; ++i) {
    int p = i * 512 + tid;
    int wl = (p & 7) ^ ((p >> 3) & 7);
    int row = ((p >> 3) << 1) | (wl >> 2);
    int kc = (wl & 3) * 8;
    int ra = m0 + row; if (ra > MROWS - 1) ra = MROWS - 1;
    int rb = n0 + row; if (rb > N - 1) rb = N - 1;
    asrc[i] = A + (long)ra * KD + kc;
    bsrc[i] = Bt + (long)rb * KD + kc;
  }

#define STAGEA(bi, kt_, i) \
  __builtin_amdgcn_global_load_lds((const AS1 void*)(asrc[i] + (kt_) * 32), \
      (AS3 void*)(&Lds[(bi) * 8192 + (i * 512 + tid) * 8]), 16, 0, 0)
#define STAGEB(bi, kt_, i) \
  __builtin_amdgcn_global_load_lds((const AS1 void*)(bsrc[i] + (kt_) * 32), \
      (AS3 void*)(&Lds[32768 + (bi) * 8192 + (i * 512 + tid) * 8]), 16, 0, 0)
#define LDA(dst, abase, mi) { const int row_ = wr * 128 + (mi) * 16 + lrow; \
  dst = *(const short8*)&Lds[(abase) + ((row_ >> 1) << 6) + \
      (((((row_ & 1) << 2) + lg) ^ ((row_ >> 1) & 7)) << 3)]; }
#define LDB(dst, bbase, nj) { const int row_ = wc * 64 + (nj) * 16 + lrow; \
  dst = *(const short8*)&Lds[(bbase) + ((row_ >> 1) << 6) + \
      (((((row_ & 1) << 2) + lg) ^ ((row_ >> 1) & 7)) << 3)]; }
#define MFMA16(a, b, c) __builtin_amdgcn_mfma_f32_16x16x32_bf16(a, b, c, 0, 0, 0)

  float4_ acc[8][4];
#pragma unroll
  for (int mi = 0; mi < 8; ++mi)
#pragma unroll
    for (int nj = 0; nj < 4; ++nj) acc[mi][nj] = (float4_)(0.f);

  // prologue: stage tiles 0,1,2 into bufs 0,1,2 (12 loads in flight)
  STAGEA(0, 0, 0); STAGEA(0, 0, 1); STAGEB(0, 0, 0); STAGEB(0, 0, 1);
  STAGEA(1, 1, 0); STAGEA(1, 1, 1); STAGEB(1, 1, 0); STAGEB(1, 1, 1);
  STAGEA(2, 2, 0); STAGEA(2, 2, 1); STAGEB(2, 2, 0); STAGEB(2, 2, 1);
  asm volatile("s_waitcnt vmcnt(8)" ::: "memory");   // tile 0 landed
  BARM();

  for (int kt = 0; kt < NTK; ++kt) {
    const int cur = kt & 3, st = (kt + 3) & 3;
    const bool dost = (kt + 3) < NTK;
    const int abase = cur * 8192, bbase = 32768 + cur * 8192;
    short8 a0, a1, a2, a3, bb0, bb1, bb2, bb3;
    // ---- phase 0: stage tile kt+3 (issue-early); mi 0-3 x nj 0-3 ----
    if (dost) {
      STAGEA(st, kt + 3, 0); STAGEA(st, kt + 3, 1);
      STAGEB(st, kt + 3, 0); STAGEB(st, kt + 3, 1);
    }
    LDA(a0, abase, 0); LDA(a1, abase, 1); LDA(a2, abase, 2); LDA(a3, abase, 3);
    LDB(bb0, bbase, 0); LDB(bb1, bbase, 1); LDB(bb2, bbase, 2); LDB(bb3, bbase, 3);
    BARM();
    asm volatile("s_waitcnt lgkmcnt(0)" ::: "memory");
    __builtin_amdgcn_sched_barrier(0);
    __builtin_amdgcn_s_setprio(1);
    acc[0][0] = MFMA16(a0, bb0, acc[0][0]);
    acc[0][1] = MFMA16(a0, bb1, acc[0][1]);
    acc[0][2] = MFMA16(a0, bb2, acc[0][2]);
    acc[0][3] = MFMA16(a0, bb3, acc[0][3]);
    acc[1][0] = MFMA16(a1, bb0, acc[1][0]);
    acc[1][1] = MFMA16(a1, bb1, acc[1][1]);
    acc[1][2] = MFMA16(a1, bb2, acc[1][2]);
    acc[1][3] = MFMA16(a1, bb3, acc[1][3]);
    acc[2][0] = MFMA16(a2, bb0, acc[2][0]);
    acc[2][1] = MFMA16(a2, bb1, acc[2][1]);
    acc[2][2] = MFMA16(a2, bb2, acc[2][2]);
    acc[2][3] = MFMA16(a2, bb3, acc[2][3]);
    acc[3][0] = MFMA16(a3, bb0, acc[3][0]);
    acc[3][1] = MFMA16(a3, bb1, acc[3][1]);
    acc[3][2] = MFMA16(a3, bb2, acc[3][2]);
    acc[3][3] = MFMA16(a3, bb3, acc[3][3]);
    __builtin_amdgcn_s_setprio(0);
    BARM();
    // ---- phase 1: mi 4-7 x nj 0-3 (B frags reused); counted vmcnt, never 0 mid-loop ----
    LDA(a0, abase, 4); LDA(a1, abase, 5); LDA(a2, abase, 6); LDA(a3, abase, 7);
    if (dost)                asm volatile("s_waitcnt vmcnt(8)" ::: "memory");  // kt+1 landed
    else if (kt == NTK - 3)  asm volatile("s_waitcnt vmcnt(4)" ::: "memory");  // kt+1 landed
    else if (kt == NTK - 2)  asm volatile("s_waitcnt vmcnt(0)" ::: "memory");  // last tile landed
    BARM();
    asm volatile("s_waitcnt lgkmcnt(0)" ::: "memory");
    __builtin_amdgcn_sched_barrier(0);
    __builtin_amdgcn_s_setprio(1);
    acc[4][0] = MFMA16(a0, bb0, acc[4][0]);
    acc[4][1] = MFMA16(a0, bb1, acc[4][1]);
    acc[4][2] = MFMA16(a0, bb2, acc[4][2]);
    acc[4][3] = MFMA16(a0, bb3, acc[4][3]);
    acc[5][0] = MFMA16(a1, bb0, acc[5][0]);
    acc[5][1] = MFMA16(a1, bb1, acc[5][1]);
    acc[5][2] = MFMA16(a1, bb2, acc[5][2]);
    acc[5][3] = MFMA16(a1, bb3, acc[5][3]);
    acc[6][0] = MFMA16(a2, bb0, acc[6][0]);
    acc[6][1] = MFMA16(a2, bb1, acc[6][1]);
    acc[6][2] = MFMA16(a2, bb2, acc[6][2]);
    acc[6][3] = MFMA16(a2, bb3, acc[6][3]);
    acc[7][0] = MFMA16(a3, bb0, acc[7][0]);
    acc[7][1] = MFMA16(a3, bb1, acc[7][1]);
    acc[7][2] = MFMA16(a3, bb2, acc[7][2]);
    acc[7][3] = MFMA16(a3, bb3, acc[7][3]);
    __builtin_amdgcn_s_setprio(0);
    BARM();
  }

  // epilogue: 16x16 C layout row = lg*4 + r, col = lrow
  float bias[4];
#pragma unroll
  for (int nj = 0; nj < 4; ++nj) {
    int cn = n0 + wc * 64 + nj * 16 + lrow;
    float bv_ = 0.f;
    if (cn < N) bv_ = (N == HDIM) ? b0[cn]
                                  : (cn < HDIM ? b0[cn] : (cn < 2 * HDIM ? b1[cn - HDIM] : b2[cn - 2 * HDIM]));
    bias[nj] = bv_;
  }
#pragma unroll
  for (int mi = 0; mi < 8; ++mi)
#pragma unroll
    for (int r = 0; r < 4; ++r) {
      int m = m0 + wr * 128 + mi * 16 + lg * 4 + r;
      if (m >= MROWS) continue;
#pragma unroll
      for (int nj = 0; nj < 4; ++nj) {
        int cn = n0 + wc * 64 + nj * 16 + lrow;
        if (cn >= N) continue;
        float v = acc[mi][nj][r] + bias[nj];
        if (OUTF32) ((float*)Cout)[(long)m * N + cn] = v;
        else        ((short*)Cout)[(long)m * N + cn] = f2bf(v);
      }
    }
#undef STAGEA
#undef STAGEB
#undef LDA
#undef LDB
#undef MFMA16
}

// ---------------- rotary on Q only (vectorized short8; K handled in fragpack) ----------------
__global__ __launch_bounds__(256) void rotary_q(short* __restrict__ QKV,
                                                const int* __restrict__ rowsp,
                                                const int* __restrict__ colsp) {
  int idx = blockIdx.x * 256 + threadIdx.x;
  if (idx >= MROWS * NH * 4) return;
  const int qt = idx & 3;
  const int hm = idx >> 2;
  const int h = hm % NH, m = hm / NH;
  const int s = m % SEQ;
  const int cols = colsp[0], rws = rowsp[0];
  const int off = (SEQ != rws * cols) ? 1 : 0;
  int gid = s - off; if (gid < 0) gid = 0;
  const float frow = (float)(gid / cols), fcol = (float)(gid % cols);
  union { short sh[24]; short8 v[3]; } u;
  short* p = QKV + (long)m * N_QKV + h * DH + qt * 24;
  u.v[0] = *(short8*)p; u.v[1] = *(short8*)(p + 8); u.v[2] = *(short8*)(p + 16);
#pragma unroll
  for (int t = 0; t < 8; ++t) {
    int j = qt * 8 + t;
    float invf = exp2f((float)(3 * j) * (-13.287712379549449f / 192.0f));
    float st, ct, sp, cp;
    __sincosf(frow * invf, &st, &ct);
    __sincosf(fcol * invf, &sp, &cp);
    float x0 = bf2f(u.sh[3 * t]), x1 = bf2f(u.sh[3 * t + 1]), x2 = bf2f(u.sh[3 * t + 2]);
    u.sh[3 * t]     = f2bf( cp * x0 + sp * st * x1 + sp * ct * x2);
    u.sh[3 * t + 1] = f2bf( ct * x1 - st * x2);
    u.sh[3 * t + 2] = f2bf(-sp * x0 + cp * st * x1 + cp * ct * x2);
  }
  *(short8*)p = u.v[0]; *(short8*)(p + 8) = u.v[1]; *(short8*)(p + 16) = u.v[2];
}

// ---------------- fragment prepack (+K rotary fused) ----------------
__global__ __launch_bounds__(256) void fragpack(const short* __restrict__ QKV,
                                                short* __restrict__ Kf,
                                                short* __restrict__ Vf,
                                                const int* __restrict__ rowsp,
                                                const int* __restrict__ colsp) {
  __shared__ short L[64 * 96];  // [kv=2][row 32][96]
  const int t = blockIdx.x, bh = blockIdx.y;
  const int b = bh / NH, h = bh % NH;
  const int tid = threadIdx.x;
#pragma unroll
  for (int i = 0; i < 3; ++i) {
    int cc = i * 256 + tid;
    int kv = cc / 384;
    int rm = cc % 384;
    int r = rm / 12, m = rm % 12;
    int s = t * 32 + r; if (s > SEQ - 1) s = SEQ - 1;
    const short* src = QKV + (long)(b * SEQ + s) * N_QKV + (kv ? 2 * HDIM : HDIM) + h * DH + m * 8;
    *(short8*)&L[cc * 8] = *(const short8*)src;
  }
  __syncthreads();
  {
    const int cols = colsp[0], rws = rowsp[0];
    const int off = (SEQ != rws * cols) ? 1 : 0;
#pragma unroll
    for (int i = 0; i < 4; ++i) {
      int idx2 = i * 256 + tid;      // 1024 = 32 rows x 32 triplets
      int r = idx2 >> 5, j = idx2 & 31;
      int s = t * 32 + r; if (s > SEQ - 1) s = SEQ - 1;
      int gid = s - off; if (gid < 0) gid = 0;
      float invf = exp2f((float)(3 * j) * (-13.287712379549449f / 192.0f));
      float st, ct, sp, cp;
      __sincosf((float)(gid / cols) * invf, &st, &ct);
      __sincosf((float)(gid % cols) * invf, &sp, &cp);
      short* pp = &L[r * 96 + 3 * j];
      float x0 = bf2f(pp[0]), x1 = bf2f(pp[1]), x2 = bf2f(pp[2]);
      pp[0] = f2bf( cp * x0 + sp * st * x1 + sp * ct * x2);
      pp[1] = f2bf( ct * x1 - st * x2);
      pp[2] = f2bf(-sp * x0 + cp * st * x1 + cp * ct * x2);
    }
  }
  __syncthreads();
#pragma unroll
  for (int i = 0; i < 3; ++i) {
    int oc = i * 256 + tid;
    if (oc < 384) {
      int c = oc / 64, ll = oc & 63;
      int qi = ll & 31, hi = ll >> 5;
      short8 v = *(const short8*)&L[qi * 96 + c * 16 + hi * 8];
      *(short8*)(Kf + (((long)(bh * 33 + t) * 6 + c) * 64 + ll) * 8) = v;
    } else {
      int oc2 = oc - 384;
      int d = oc2 / 128, sl = (oc2 / 64) & 1, ll = oc2 & 63;
      int qi = ll & 31, hi = ll >> 5;
      short8 v;
#pragma unroll
      for (int j = 0; j < 8; ++j)
        v[j] = L[32 * 96 + (sl * 16 + hi * 8 + j) * 96 + d * 32 + qi];
      *(short8*)(Vf + ((((long)(bh * 33 + t) * 3 + d) * 2 + sl) * 64 + ll) * 8) = v;
    }
  }
}

// ---------------- flash attention, swapped-operand 32x32, prepacked K/V ----------------
__global__ __launch_bounds__(128, 3) void attn_kernel(const short* __restrict__ QKV,
                                                      const short* __restrict__ Kf,
                                                      const short* __restrict__ Vf,
                                                      short* __restrict__ CTX) {
  const int tid = threadIdx.x;
  const int l = tid & 63, w = tid >> 6;
  const int qi = l & 31, hi = l >> 5;
  const int bid = blockIdx.x;
  const int xcd = bid & 7, jj = bid >> 3;
  const int bh = xcd * 12 + jj / 17;
  const int qb = jj % 17;
  const int b = bh / NH, h = bh % NH;
  const int s = qb * 64 + w * 32 + qi;
  const int sq = s > SEQ - 1 ? SEQ - 1 : s;

  const float scale = 0.1020620726159658f;  // 96^-0.5
  const short* Qr = QKV + (long)(b * SEQ + sq) * N_QKV + h * DH;
  short8 qf[6];
#pragma unroll
  for (int c = 0; c < 6; ++c) {
    short8 v = *(const short8*)(Qr + c * 16 + hi * 8);
#pragma unroll
    for (int j = 0; j < 8; ++j) v[j] = f2bf(bf2f(v[j]) * scale);
    qf[c] = v;
  }

  const short* Kb = Kf + (long)bh * 33 * 6 * 64 * 8;
  const short* Vb = Vf + (long)bh * 33 * 6 * 64 * 8;

  f32x16 ctxv[3];
#pragma unroll
  for (int d = 0; d < 3; ++d) ctxv[d] = (f32x16)(0.f);
  float m_ = -1e30f, l_ = 0.f;

  for (int t = 0; t < 33; ++t) {
    f32x16 S = (f32x16)(0.f);
#pragma unroll
    for (int c = 0; c < 6; ++c) {
      short8 kf = *(const short8*)(Kb + (((long)t * 6 + c) * 64 + l) * 8);
      S = __builtin_amdgcn_mfma_f32_32x32x16_bf16(kf, qf[c], S, 0, 0, 0);
    }
    if (t == 32) {
      S[0] = hi ? -1e30f : S[0];
#pragma unroll
      for (int r = 1; r < 16; ++r) S[r] = -1e30f;
    }
    float tm = S[0];
#pragma unroll
    for (int r = 1; r < 16; ++r) tm = fmaxf(tm, S[r]);
    tm = fmaxf(tm, __shfl_xor(tm, 32));
    if (!__all(tm - m_ <= 8.f)) {
      float mn = fmaxf(m_, tm);
      float alpha = __expf(m_ - mn);
      m_ = mn;
      l_ *= alpha;
#pragma unroll
      for (int d = 0; d < 3; ++d)
#pragma unroll
        for (int r = 0; r < 16; ++r) ctxv[d][r] *= alpha;
    }
    float ts = 0.f;
#pragma unroll
    for (int r = 0; r < 16; ++r) { float p = __expf(S[r] - m_); S[r] = p; ts += p; }
    ts += __shfl_xor(ts, 32);
    l_ += ts;

    unsigned pk_[8];
#pragma unroll
    for (int j = 0; j < 8; ++j)
      pk_[j] = (unsigned)(unsigned short)f2bf(S[2 * j]) |
               ((unsigned)(unsigned short)f2bf(S[2 * j + 1]) << 16);
    unsigned s0 = hi ? pk_[0] : pk_[2];
    unsigned s1 = hi ? pk_[1] : pk_[3];
    unsigned s2 = hi ? pk_[4] : pk_[6];
    unsigned s3 = hi ? pk_[5] : pk_[7];
    unsigned r0 = __shfl_xor(s0, 32);
    unsigned r1 = __shfl_xor(s1, 32);
    unsigned r2 = __shfl_xor(s2, 32);
    unsigned r3 = __shfl_xor(s3, 32);
    union PF { unsigned u[4]; short8 s8; } f0, f1;
    f0.u[0] = hi ? r0 : pk_[0];
    f0.u[1] = hi ? r1 : pk_[1];
    f0.u[2] = hi ? pk_[2] : r0;
    f0.u[3] = hi ? pk_[3] : r1;
    f1.u[0] = hi ? r2 : pk_[4];
    f1.u[1] = hi ? r3 : pk_[5];
    f1.u[2] = hi ? pk_[6] : r2;
    f1.u[3] = hi ? pk_[7] : r3;

#pragma unroll
    for (int d = 0; d < 3; ++d) {
      const short* Vr = Vb + (((long)t * 3 + d) * 2 * 64) * 8;
      short8 vf0 = *(const short8*)(Vr + l * 8);
      ctxv[d] = __builtin_amdgcn_mfma_f32_32x32x16_bf16(vf0, f0.s8, ctxv[d], 0, 0, 0);
      short8 vf1 = *(const short8*)(Vr + (64 + l) * 8);
      ctxv[d] = __builtin_amdgcn_mfma_f32_32x32x16_bf16(vf1, f1.s8, ctxv[d], 0, 0, 0);
    }
  }

  float invl = 1.f / l_;
  if (s <= SEQ - 1) {
    short* Cr = CTX + (long)(b * SEQ + s) * HDIM + h * DH;
#pragma unroll
    for (int d = 0; d < 3; ++d)
#pragma unroll
      for (int g = 0; g < 4; ++g) {
        short4_ o;
#pragma unroll
        for (int r = 0; r < 4; ++r) o[r] = f2bf(ctxv[d][4 * g + r] * invl);
        *(short4_*)(Cr + d * 32 + 8 * g + 4 * hi) = o;
      }
  }
}

extern "C" void kernel_launch(void* const* d_in, const int* in_sizes, int n_in,
                              void* d_out, int out_size, void* d_ws, size_t ws_size,
                              hipStream_t stream) {
  const float* hs = (const float*)d_in[0];
  const float* Wq = (const float*)d_in[1];
  const float* bq = (const float*)d_in[2];
  const float* Wk = (const float*)d_in[3];
  const float* bk = (const float*)d_in[4];
  const float* Wv = (const float*)d_in[5];
  const float* bv = (const float*)d_in[6];
  const float* Wo = (const float*)d_in[7];
  const float* bo = (const float*)d_in[8];
  const int* rows = (const int*)d_in[9];
  const int* cols = (const int*)d_in[10];
  float* out = (float*)d_out;

  char* ws = (char*)d_ws;
  short* X   = (short*)(ws);               // 8200*1152*2      = 18,892,800
  short* Wt  = (short*)(ws + 18892800);    // 3456*1152*2      =  7,962,624
  short* Wot = (short*)(ws + 26855424);    // 1152*1152*2      =  2,654,208
  short* QKV = (short*)(ws + 29509632);    // 8200*3456*2      = 56,678,400
  short* Vf  = (short*)(ws + 86188032);    // 96*33*6*64*16B   = 19,464,192
  short* CTX = (short*)(ws + 105652224);   // 8200*1152*2      = 18,892,800  (end 124,545,024)
  short* Kf  = (short*)(ws);               // 19,464,192 — reuses X+Wt region (dead after gemm<0>)

  convx<<<9225, 256, 0, stream>>>(hs, X);
  convw_t<<<dim3(18, 18, 3), 256, 0, stream>>>(Wq, Wk, Wv, Wt);
  convw_t<<<dim3(18, 18, 1), 256, 0, stream>>>(Wo, Wo, Wo, Wot);
  gemm256<0><<<462, 512, 0, stream>>>(X, Wt, bq, bk, bv, QKV, N_QKV, 33);   // 33 x 14 tiles
  rotary_q<<<1538, 256, 0, stream>>>(QKV, rows, cols);
  fragpack<<<dim3(33, 96), 256, 0, stream>>>(QKV, Kf, Vf, rows, cols);
  attn_kernel<<<1632, 128, 0, stream>>>(QKV, Kf, Vf, CTX);
  gemm256<1><<<165, 512, 0, stream>>>(CTX, Wot, bo, bo, bo, out, HDIM, 33); // 33 x 5 tiles
}

// Round 9
// 287.224 us; speedup vs baseline: 1.0063x; 1.0063x over previous
//
#include <hip/hip_runtime.h>
#include <stdint.h>

#define BATCH 8
#define SEQ   1025
#define HDIM  1152
#define NH    12
#define DH    96
#define MROWS (BATCH*SEQ)   // 8200
#define N_QKV (3*HDIM)      // 3456
#define KD    HDIM          // 1152 (K of both GEMMs)
#define NTK   36            // K-tiles of 32

typedef __attribute__((ext_vector_type(8))) short short8;
typedef __attribute__((ext_vector_type(4))) short short4_;
typedef __attribute__((ext_vector_type(4))) float float4_;
typedef __attribute__((ext_vector_type(16))) float f32x16;

#define AS1 __attribute__((address_space(1)))
#define AS3 __attribute__((address_space(3)))
#define BARM() do { asm volatile("" ::: "memory"); __builtin_amdgcn_s_barrier(); asm volatile("" ::: "memory"); } while (0)

__device__ inline float bf2f(short s) {
  union { unsigned u; float f; } x; x.u = ((unsigned)(unsigned short)s) << 16; return x.f;
}
__device__ inline short f2bf(float f) {
  union { float f; unsigned u; } x; x.f = f;
  unsigned r = (x.u + 0x7fffu + ((x.u >> 16) & 1u)) >> 16;
  return (short)r;
}

// ---------------- converts ----------------
__global__ __launch_bounds__(256) void convx(const float* __restrict__ hs, short* __restrict__ X) {
  int i = blockIdx.x * 256 + threadIdx.x;  // exactly 2361600 threads
  float4_ v = ((const float4_*)hs)[i];
  short4_ o;
  o[0] = f2bf(v[0]); o[1] = f2bf(v[1]); o[2] = f2bf(v[2]); o[3] = f2bf(v[3]);
  ((short4_*)X)[i] = o;
}

// tiled transpose-cast: Wt[z*1152 + n][k] = W_z[k][n]
__global__ __launch_bounds__(256) void convw_t(const float* __restrict__ W0,
                                               const float* __restrict__ W1,
                                               const float* __restrict__ W2,
                                               short* __restrict__ Wt) {
  __shared__ float T[64][65];
  const int z = blockIdx.z;
  const float* W = z == 0 ? W0 : (z == 1 ? W1 : W2);
  const int n0 = blockIdx.x * 64, k0 = blockIdx.y * 64;
  const int tid = threadIdx.x;
  const int r = tid >> 2, cq = (tid & 3) * 16;
#pragma unroll
  for (int u = 0; u < 4; ++u) {
    float4_ v = *(const float4_*)&W[(long)(k0 + r) * HDIM + n0 + cq + u * 4];
    T[r][cq + u * 4 + 0] = v[0]; T[r][cq + u * 4 + 1] = v[1];
    T[r][cq + u * 4 + 2] = v[2]; T[r][cq + u * 4 + 3] = v[3];
  }
  __syncthreads();
  const int n = tid >> 2, kq = (tid & 3) * 16;
  short out[16];
#pragma unroll
  for (int u = 0; u < 16; ++u) out[u] = f2bf(T[kq + u][n]);
  short* dst = Wt + (long)(z * HDIM + n0 + n) * KD + k0 + kq;
  *(short8*)dst = *(short8*)&out[0];
  *(short8*)(dst + 8) = *(short8*)&out[8];
}

// ---------------- GEMM 128x128, 4-wave, TRIPLE-buffered BK=32, 3 blocks/CU ----------------
// Rationale: the 256²/1-block-per-CU 2-phase structure sits at the documented ~600 TF
// structural ceiling (m233) — nothing fills its barrier stalls. At 48KB LDS / 256 thr
// we get 3 blocks/CU, and cross-block wave overlap (m114) fills the stalls (m97: 874 TF).
// Swizzle (round-6 verified, 0 conflicts): rows of 32 bf16 = 64B; line = row>>1 (128B),
// 16B-slot = (row&1)*4+lg, phys_slot = slot ^ (line&7). Staging inverse on per-lane
// SOURCE (global_load_lds writes linearly, Rule 21): p -> wl=(p&7)^((p>>3)&7);
// row=(p>>3)*2+(wl>>2); kc=(wl&3)*8.
// Pipeline: tile kt reads buf kt%3; tiles kt+1 (landed), kt+2 (in flight) in other bufs.
// Counted vmcnt(4) per tile (oldest 4 = tile kt+1), vmcnt(0) only at the 2-tile tail.
// RACE FIX (round-8 post-mortem): s_waitcnt lgkmcnt(0) BEFORE the closing barrier —
// MFMAs are register-only and can sink past the barrier, leaving ds_reads of buf kt%3
// outstanding while another wave stages tile kt+3 into that same buffer (WAR). Draining
// lgkm before s_barrier (ISA §8) closes it; compiler still schedules the body freely.
template<int OUTF32>
__global__ __launch_bounds__(256, 3) void gemm256(
    const short* __restrict__ A, const short* __restrict__ Bt,
    const float* __restrict__ b0, const float* __restrict__ b1, const float* __restrict__ b2,
    void* __restrict__ Cout, const int N, const int MT) {
  __shared__ alignas(16) short Lds[24576];  // 48KB: A bufs [3][4096], B bufs at 12288+[3][4096]
  const int tid = threadIdx.x;
  const int l = tid & 63, w = tid >> 6;
  const int lrow = l & 15, lg = l >> 4;
  const int wr = w >> 1, wc = w & 1;

  // bijective XCD swizzle (m204)
  const int nwg = gridDim.x;
  const int qq = nwg >> 3, r8 = nwg & 7;
  const int xcd = blockIdx.x & 7, loc = blockIdx.x >> 3;
  const int wg = (xcd < r8 ? xcd * (qq + 1) : r8 * (qq + 1) + (xcd - r8) * qq) + loc;
  const int mt = wg % MT, nt = wg / MT;
  const int m0 = mt * 128, n0 = nt * 128;

  // staging sources (inverse swizzle); 2 chunks per thread per matrix
  const short* asrc[2]; const short* bsrc[2];
#pragma unroll
  for (int i = 0; i < 2; ++i) {
    int p = i * 256 + tid;
    int wl = (p & 7) ^ ((p >> 3) & 7);
    int row = ((p >> 3) << 1) | (wl >> 2);
    int kc = (wl & 3) * 8;
    int ra = m0 + row; if (ra > MROWS - 1) ra = MROWS - 1;
    int rb = n0 + row; if (rb > N - 1) rb = N - 1;
    asrc[i] = A + (long)ra * KD + kc;
    bsrc[i] = Bt + (long)rb * KD + kc;
  }

#define STAGEA(bi, kt_, i) \
  __builtin_amdgcn_global_load_lds((const AS1 void*)(asrc[i] + (kt_) * 32), \
      (AS3 void*)(&Lds[(bi) * 4096 + (i * 256 + tid) * 8]), 16, 0, 0)
#define STAGEB(bi, kt_, i) \
  __builtin_amdgcn_global_load_lds((const AS1 void*)(bsrc[i] + (kt_) * 32), \
      (AS3 void*)(&Lds[12288 + (bi) * 4096 + (i * 256 + tid) * 8]), 16, 0, 0)
#define LDA(dst, abase, mi) { const int row_ = wr * 64 + (mi) * 16 + lrow; \
  dst = *(const short8*)&Lds[(abase) + ((row_ >> 1) << 6) + \
      (((((row_ & 1) << 2) + lg) ^ ((row_ >> 1) & 7)) << 3)]; }
#define LDB(dst, bbase, nj) { const int row_ = wc * 64 + (nj) * 16 + lrow; \
  dst = *(const short8*)&Lds[(bbase) + ((row_ >> 1) << 6) + \
      (((((row_ & 1) << 2) + lg) ^ ((row_ >> 1) & 7)) << 3)]; }
#define MFMA16(a, b, c) __builtin_amdgcn_mfma_f32_16x16x32_bf16(a, b, c, 0, 0, 0)

  float4_ acc[4][4];
#pragma unroll
  for (int mi = 0; mi < 4; ++mi)
#pragma unroll
    for (int nj = 0; nj < 4; ++nj) acc[mi][nj] = (float4_)(0.f);

  // prologue: stage tiles 0,1 into bufs 0,1 (8 loads in flight)
  STAGEA(0, 0, 0); STAGEA(0, 0, 1); STAGEB(0, 0, 0); STAGEB(0, 0, 1);
  STAGEA(1, 1, 0); STAGEA(1, 1, 1); STAGEB(1, 1, 0); STAGEB(1, 1, 1);
  asm volatile("s_waitcnt vmcnt(4)" ::: "memory");   // tile 0 landed
  BARM();

  for (int kt = 0; kt < NTK; ++kt) {
    const int cur = kt % 3, st = (kt + 2) % 3;
    const bool dost = (kt + 2) < NTK;
    const int abase = cur * 4096, bbase = 12288 + cur * 4096;
    // stage tile kt+2 (issue-early; lands under this tile's compute)
    if (dost) {
      STAGEA(st, kt + 2, 0); STAGEA(st, kt + 2, 1);
      STAGEB(st, kt + 2, 0); STAGEB(st, kt + 2, 1);
    }
    short8 a0, a1, a2, a3, bb0, bb1, bb2, bb3;
    LDB(bb0, bbase, 0); LDB(bb1, bbase, 1); LDB(bb2, bbase, 2); LDB(bb3, bbase, 3);
    LDA(a0, abase, 0); LDA(a1, abase, 1); LDA(a2, abase, 2); LDA(a3, abase, 3);
    acc[0][0] = MFMA16(a0, bb0, acc[0][0]);
    acc[0][1] = MFMA16(a0, bb1, acc[0][1]);
    acc[0][2] = MFMA16(a0, bb2, acc[0][2]);
    acc[0][3] = MFMA16(a0, bb3, acc[0][3]);
    acc[1][0] = MFMA16(a1, bb0, acc[1][0]);
    acc[1][1] = MFMA16(a1, bb1, acc[1][1]);
    acc[1][2] = MFMA16(a1, bb2, acc[1][2]);
    acc[1][3] = MFMA16(a1, bb3, acc[1][3]);
    acc[2][0] = MFMA16(a2, bb0, acc[2][0]);
    acc[2][1] = MFMA16(a2, bb1, acc[2][1]);
    acc[2][2] = MFMA16(a2, bb2, acc[2][2]);
    acc[2][3] = MFMA16(a2, bb3, acc[2][3]);
    acc[3][0] = MFMA16(a3, bb0, acc[3][0]);
    acc[3][1] = MFMA16(a3, bb1, acc[3][1]);
    acc[3][2] = MFMA16(a3, bb2, acc[3][2]);
    acc[3][3] = MFMA16(a3, bb3, acc[3][3]);
    // tile boundary: counted vmcnt (oldest 4 = tile kt+1), drain own LDS reads, ONE barrier
    if (dost)                asm volatile("s_waitcnt vmcnt(4)" ::: "memory");
    else if (kt == NTK - 2)  asm volatile("s_waitcnt vmcnt(0)" ::: "memory");
    asm volatile("s_waitcnt lgkmcnt(0)" ::: "memory");   // race fix: reads drained pre-barrier
    BARM();
  }

  // epilogue: 16x16 C layout row = lg*4 + r, col = lrow
  float bias[4];
#pragma unroll
  for (int nj = 0; nj < 4; ++nj) {
    int cn = n0 + wc * 64 + nj * 16 + lrow;
    float bv_ = 0.f;
    if (cn < N) bv_ = (N == HDIM) ? b0[cn]
                                  : (cn < HDIM ? b0[cn] : (cn < 2 * HDIM ? b1[cn - HDIM] : b2[cn - 2 * HDIM]));
    bias[nj] = bv_;
  }
#pragma unroll
  for (int mi = 0; mi < 4; ++mi)
#pragma unroll
    for (int r = 0; r < 4; ++r) {
      int m = m0 + wr * 64 + mi * 16 + lg * 4 + r;
      if (m >= MROWS) continue;
#pragma unroll
      for (int nj = 0; nj < 4; ++nj) {
        int cn = n0 + wc * 64 + nj * 16 + lrow;
        if (cn >= N) continue;
        float v = acc[mi][nj][r] + bias[nj];
        if (OUTF32) ((float*)Cout)[(long)m * N + cn] = v;
        else        ((short*)Cout)[(long)m * N + cn] = f2bf(v);
      }
    }
#undef STAGEA
#undef STAGEB
#undef LDA
#undef LDB
#undef MFMA16
}

// ---------------- rotary on Q only (vectorized short8; K handled in fragpack) ----------------
__global__ __launch_bounds__(256) void rotary_q(short* __restrict__ QKV,
                                                const int* __restrict__ rowsp,
                                                const int* __restrict__ colsp) {
  int idx = blockIdx.x * 256 + threadIdx.x;
  if (idx >= MROWS * NH * 4) return;
  const int qt = idx & 3;
  const int hm = idx >> 2;
  const int h = hm % NH, m = hm / NH;
  const int s = m % SEQ;
  const int cols = colsp[0], rws = rowsp[0];
  const int off = (SEQ != rws * cols) ? 1 : 0;
  int gid = s - off; if (gid < 0) gid = 0;
  const float frow = (float)(gid / cols), fcol = (float)(gid % cols);
  union { short sh[24]; short8 v[3]; } u;
  short* p = QKV + (long)m * N_QKV + h * DH + qt * 24;
  u.v[0] = *(short8*)p; u.v[1] = *(short8*)(p + 8); u.v[2] = *(short8*)(p + 16);
#pragma unroll
  for (int t = 0; t < 8; ++t) {
    int j = qt * 8 + t;
    float invf = exp2f((float)(3 * j) * (-13.287712379549449f / 192.0f));
    float st, ct, sp, cp;
    __sincosf(frow * invf, &st, &ct);
    __sincosf(fcol * invf, &sp, &cp);
    float x0 = bf2f(u.sh[3 * t]), x1 = bf2f(u.sh[3 * t + 1]), x2 = bf2f(u.sh[3 * t + 2]);
    u.sh[3 * t]     = f2bf( cp * x0 + sp * st * x1 + sp * ct * x2);
    u.sh[3 * t + 1] = f2bf( ct * x1 - st * x2);
    u.sh[3 * t + 2] = f2bf(-sp * x0 + cp * st * x1 + cp * ct * x2);
  }
  *(short8*)p = u.v[0]; *(short8*)(p + 8) = u.v[1]; *(short8*)(p + 16) = u.v[2];
}

// ---------------- fragment prepack (+K rotary fused) ----------------
__global__ __launch_bounds__(256) void fragpack(const short* __restrict__ QKV,
                                                short* __restrict__ Kf,
                                                short* __restrict__ Vf,
                                                const int* __restrict__ rowsp,
                                                const int* __restrict__ colsp) {
  __shared__ short L[64 * 96];  // [kv=2][row 32][96]
  const int t = blockIdx.x, bh = blockIdx.y;
  const int b = bh / NH, h = bh % NH;
  const int tid = threadIdx.x;
#pragma unroll
  for (int i = 0; i < 3; ++i) {
    int cc = i * 256 + tid;
    int kv = cc / 384;
    int rm = cc % 384;
    int r = rm / 12, m = rm % 12;
    int s = t * 32 + r; if (s > SEQ - 1) s = SEQ - 1;
    const short* src = QKV + (long)(b * SEQ + s) * N_QKV + (kv ? 2 * HDIM : HDIM) + h * DH + m * 8;
    *(short8*)&L[cc * 8] = *(const short8*)src;
  }
  __syncthreads();
  {
    const int cols = colsp[0], rws = rowsp[0];
    const int off = (SEQ != rws * cols) ? 1 : 0;
#pragma unroll
    for (int i = 0; i < 4; ++i) {
      int idx2 = i * 256 + tid;      // 1024 = 32 rows x 32 triplets
      int r = idx2 >> 5, j = idx2 & 31;
      int s = t * 32 + r; if (s > SEQ - 1) s = SEQ - 1;
      int gid = s - off; if (gid < 0) gid = 0;
      float invf = exp2f((float)(3 * j) * (-13.287712379549449f / 192.0f));
      float st, ct, sp, cp;
      __sincosf((float)(gid / cols) * invf, &st, &ct);
      __sincosf((float)(gid % cols) * invf, &sp, &cp);
      short* pp = &L[r * 96 + 3 * j];
      float x0 = bf2f(pp[0]), x1 = bf2f(pp[1]), x2 = bf2f(pp[2]);
      pp[0] = f2bf( cp * x0 + sp * st * x1 + sp * ct * x2);
      pp[1] = f2bf( ct * x1 - st * x2);
      pp[2] = f2bf(-sp * x0 + cp * st * x1 + cp * ct * x2);
    }
  }
  __syncthreads();
#pragma unroll
  for (int i = 0; i < 3; ++i) {
    int oc = i * 256 + tid;
    if (oc < 384) {
      int c = oc / 64, ll = oc & 63;
      int qi = ll & 31, hi = ll >> 5;
      short8 v = *(const short8*)&L[qi * 96 + c * 16 + hi * 8];
      *(short8*)(Kf + (((long)(bh * 33 + t) * 6 + c) * 64 + ll) * 8) = v;
    } else {
      int oc2 = oc - 384;
      int d = oc2 / 128, sl = (oc2 / 64) & 1, ll = oc2 & 63;
      int qi = ll & 31, hi = ll >> 5;
      short8 v;
#pragma unroll
      for (int j = 0; j < 8; ++j)
        v[j] = L[32 * 96 + (sl * 16 + hi * 8 + j) * 96 + d * 32 + qi];
      *(short8*)(Vf + ((((long)(bh * 33 + t) * 3 + d) * 2 + sl) * 64 + ll) * 8) = v;
    }
  }
}

// ---------------- flash attention, swapped-operand 32x32, prepacked K/V ----------------
__global__ __launch_bounds__(128, 3) void attn_kernel(const short* __restrict__ QKV,
                                                      const short* __restrict__ Kf,
                                                      const short* __restrict__ Vf,
                                                      short* __restrict__ CTX) {
  const int tid = threadIdx.x;
  const int l = tid & 63, w = tid >> 6;
  const int qi = l & 31, hi = l >> 5;
  const int bid = blockIdx.x;
  const int xcd = bid & 7, jj = bid >> 3;
  const int bh = xcd * 12 + jj / 17;
  const int qb = jj % 17;
  const int b = bh / NH, h = bh % NH;
  const int s = qb * 64 + w * 32 + qi;
  const int sq = s > SEQ - 1 ? SEQ - 1 : s;

  const float scale = 0.1020620726159658f;  // 96^-0.5
  const short* Qr = QKV + (long)(b * SEQ + sq) * N_QKV + h * DH;
  short8 qf[6];
#pragma unroll
  for (int c = 0; c < 6; ++c) {
    short8 v = *(const short8*)(Qr + c * 16 + hi * 8);
#pragma unroll
    for (int j = 0; j < 8; ++j) v[j] = f2bf(bf2f(v[j]) * scale);
    qf[c] = v;
  }

  const short* Kb = Kf + (long)bh * 33 * 6 * 64 * 8;
  const short* Vb = Vf + (long)bh * 33 * 6 * 64 * 8;

  f32x16 ctxv[3];
#pragma unroll
  for (int d = 0; d < 3; ++d) ctxv[d] = (f32x16)(0.f);
  float m_ = -1e30f, l_ = 0.f;

  for (int t = 0; t < 33; ++t) {
    f32x16 S = (f32x16)(0.f);
#pragma unroll
    for (int c = 0; c < 6; ++c) {
      short8 kf = *(const short8*)(Kb + (((long)t * 6 + c) * 64 + l) * 8);
      S = __builtin_amdgcn_mfma_f32_32x32x16_bf16(kf, qf[c], S, 0, 0, 0);
    }
    if (t == 32) {
      S[0] = hi ? -1e30f : S[0];
#pragma unroll
      for (int r = 1; r < 16; ++r) S[r] = -1e30f;
    }
    float tm = S[0];
#pragma unroll
    for (int r = 1; r < 16; ++r) tm = fmaxf(tm, S[r]);
    tm = fmaxf(tm, __shfl_xor(tm, 32));
    if (!__all(tm - m_ <= 8.f)) {
      float mn = fmaxf(m_, tm);
      float alpha = __expf(m_ - mn);
      m_ = mn;
      l_ *= alpha;
#pragma unroll
      for (int d = 0; d < 3; ++d)
#pragma unroll
        for (int r = 0; r < 16; ++r) ctxv[d][r] *= alpha;
    }
    float ts = 0.f;
#pragma unroll
    for (int r = 0; r < 16; ++r) { float p = __expf(S[r] - m_); S[r] = p; ts += p; }
    ts += __shfl_xor(ts, 32);
    l_ += ts;

    unsigned pk_[8];
#pragma unroll
    for (int j = 0; j < 8; ++j)
      pk_[j] = (unsigned)(unsigned short)f2bf(S[2 * j]) |
               ((unsigned)(unsigned short)f2bf(S[2 * j + 1]) << 16);
    unsigned s0 = hi ? pk_[0] : pk_[2];
    unsigned s1 = hi ? pk_[1] : pk_[3];
    unsigned s2 = hi ? pk_[4] : pk_[6];
    unsigned s3 = hi ? pk_[5] : pk_[7];
    unsigned r0 = __shfl_xor(s0, 32);
    unsigned r1 = __shfl_xor(s1, 32);
    unsigned r2 = __shfl_xor(s2, 32);
    unsigned r3 = __shfl_xor(s3, 32);
    union PF { unsigned u[4]; short8 s8; } f0, f1;
    f0.u[0] = hi ? r0 : pk_[0];
    f0.u[1] = hi ? r1 : pk_[1];
    f0.u[2] = hi ? pk_[2] : r0;
    f0.u[3] = hi ? pk_[3] : r1;
    f1.u[0] = hi ? r2 : pk_[4];
    f1.u[1] = hi ? r3 : pk_[5];
    f1.u[2] = hi ? pk_[6] : r2;
    f1.u[3] = hi ? pk_[7] : r3;

#pragma unroll
    for (int d = 0; d < 3; ++d) {
      const short* Vr = Vb + (((long)t * 3 + d) * 2 * 64) * 8;
      short8 vf0 = *(const short8*)(Vr + l * 8);
      ctxv[d] = __builtin_amdgcn_mfma_f32_32x32x16_bf16(vf0, f0.s8, ctxv[d], 0, 0, 0);
      short8 vf1 = *(const short8*)(Vr + (64 + l) * 8);
      ctxv[d] = __builtin_amdgcn_mfma_f32_32x32x16_bf16(vf1, f1.s8, ctxv[d], 0, 0, 0);
    }
  }

  float invl = 1.f / l_;
  if (s <= SEQ - 1) {
    short* Cr = CTX + (long)(b * SEQ + s) * HDIM + h * DH;
#pragma unroll
    for (int d = 0; d < 3; ++d)
#pragma unroll
      for (int g = 0; g < 4; ++g) {
        short4_ o;
#pragma unroll
        for (int r = 0; r < 4; ++r) o[r] = f2bf(ctxv[d][4 * g + r] * invl);
        *(short4_*)(Cr + d * 32 + 8 * g + 4 * hi) = o;
      }
  }
}

extern "C" void kernel_launch(void* const* d_in, const int* in_sizes, int n_in,
                              void* d_out, int out_size, void* d_ws, size_t ws_size,
                              hipStream_t stream) {
  const float* hs = (const float*)d_in[0];
  const float* Wq = (const float*)d_in[1];
  const float* bq = (const float*)d_in[2];
  const float* Wk = (const float*)d_in[3];
  const float* bk = (const float*)d_in[4];
  const float* Wv = (const float*)d_in[5];
  const float* bv = (const float*)d_in[6];
  const float* Wo = (const float*)d_in[7];
  const float* bo = (const float*)d_in[8];
  const int* rows = (const int*)d_in[9];
  const int* cols = (const int*)d_in[10];
  float* out = (float*)d_out;

  char* ws = (char*)d_ws;
  short* X   = (short*)(ws);               // 8200*1152*2      = 18,892,800
  short* Wt  = (short*)(ws + 18892800);    // 3456*1152*2      =  7,962,624
  short* Wot = (short*)(ws + 26855424);    // 1152*1152*2      =  2,654,208
  short* QKV = (short*)(ws + 29509632);    // 8200*3456*2      = 56,678,400
  short* Vf  = (short*)(ws + 86188032);    // 96*33*6*64*16B   = 19,464,192
  short* CTX = (short*)(ws + 105652224);   // 8200*1152*2      = 18,892,800  (end 124,545,024)
  short* Kf  = (short*)(ws);               // 19,464,192 — reuses X+Wt region (dead after gemm<0>)

  convx<<<9225, 256, 0, stream>>>(hs, X);
  convw_t<<<dim3(18, 18, 3), 256, 0, stream>>>(Wq, Wk, Wv, Wt);
  convw_t<<<dim3(18, 18, 1), 256, 0, stream>>>(Wo, Wo, Wo, Wot);
  gemm256<0><<<1755, 256, 0, stream>>>(X, Wt, bq, bk, bv, QKV, N_QKV, 65);  // 65 x 27 tiles
  rotary_q<<<1538, 256, 0, stream>>>(QKV, rows, cols);
  fragpack<<<dim3(33, 96), 256, 0, stream>>>(QKV, Kf, Vf, rows, cols);
  attn_kernel<<<1632, 128, 0, stream>>>(QKV, Kf, Vf, CTX);
  gemm256<1><<<585, 256, 0, stream>>>(CTX, Wot, bo, bo, bo, out, HDIM, 65); // 65 x 9 tiles
}

// Round 10
// 279.173 us; speedup vs baseline: 1.0353x; 1.0288x over previous
//
#include <hip/hip_runtime.h>
#include <stdint.h>

#define BATCH 8
#define SEQ   1025
#define HDIM  1152
#define NH    12
#define DH    96
#define MROWS (BATCH*SEQ)   // 8200
#define N_QKV (3*HDIM)      // 3456
#define KD    HDIM          // 1152 (K of both GEMMs)
#define NT2   18            // K-tiles of 64

typedef __attribute__((ext_vector_type(8))) short short8;
typedef __attribute__((ext_vector_type(4))) short short4_;
typedef __attribute__((ext_vector_type(4))) float float4_;
typedef __attribute__((ext_vector_type(16))) float f32x16;

#define AS1 __attribute__((address_space(1)))
#define AS3 __attribute__((address_space(3)))
#define BARM() do { asm volatile("" ::: "memory"); __builtin_amdgcn_s_barrier(); asm volatile("" ::: "memory"); } while (0)

__device__ inline float bf2f(short s) {
  union { unsigned u; float f; } x; x.u = ((unsigned)(unsigned short)s) << 16; return x.f;
}
__device__ inline short f2bf(float f) {
  union { float f; unsigned u; } x; x.f = f;
  unsigned r = (x.u + 0x7fffu + ((x.u >> 16) & 1u)) >> 16;
  return (short)r;
}

// ---------------- converts ----------------
__global__ __launch_bounds__(256) void convx(const float* __restrict__ hs, short* __restrict__ X) {
  int i = blockIdx.x * 256 + threadIdx.x;  // exactly 2361600 threads
  float4_ v = ((const float4_*)hs)[i];
  short4_ o;
  o[0] = f2bf(v[0]); o[1] = f2bf(v[1]); o[2] = f2bf(v[2]); o[3] = f2bf(v[3]);
  ((short4_*)X)[i] = o;
}

// tiled transpose-cast: Wt[z*1152 + n][k] = W_z[k][n]
__global__ __launch_bounds__(256) void convw_t(const float* __restrict__ W0,
                                               const float* __restrict__ W1,
                                               const float* __restrict__ W2,
                                               short* __restrict__ Wt) {
  __shared__ float T[64][65];
  const int z = blockIdx.z;
  const float* W = z == 0 ? W0 : (z == 1 ? W1 : W2);
  const int n0 = blockIdx.x * 64, k0 = blockIdx.y * 64;
  const int tid = threadIdx.x;
  const int r = tid >> 2, cq = (tid & 3) * 16;
#pragma unroll
  for (int u = 0; u < 4; ++u) {
    float4_ v = *(const float4_*)&W[(long)(k0 + r) * HDIM + n0 + cq + u * 4];
    T[r][cq + u * 4 + 0] = v[0]; T[r][cq + u * 4 + 1] = v[1];
    T[r][cq + u * 4 + 2] = v[2]; T[r][cq + u * 4 + 3] = v[3];
  }
  __syncthreads();
  const int n = tid >> 2, kq = (tid & 3) * 16;
  short out[16];
#pragma unroll
  for (int u = 0; u < 16; ++u) out[u] = f2bf(T[kq + u][n]);
  short* dst = Wt + (long)(z * HDIM + n0 + n) * KD + k0 + kq;
  *(short8*)dst = *(short8*)&out[0];
  *(short8*)(dst + 8) = *(short8*)&out[8];
}

// ---------------- GEMM 256x256, 8-wave, BK=64 in 2 k-halves, 4-phase interleave ----------------
// LDS 128KB: A = dbuf{0,1} x khalf{0,1} x [256 rows][32 k] (16KB each); B same at +64KB.
// Swizzle: 16B-slot within a 64B row: phys = lg ^ key(row), key(r)=(r&3)^((r>>2)&3)
//   (involution; quarter-wave reads -> 8 distinct positions -> 2-way = free, m136).
//   Inverse applied on per-lane staging SOURCE (gload_lds writes linearly, Rule 21).
// Pipeline (per-wave FIFO ledger; 2 loads/thread per half-tile):
//   during tile t, issue halves of t+1 in order [A-kh0, B-kh0, A-kh1, B-kh1] (phases 0-3).
//   Steady state: 8 loads in flight. Waits: vmcnt(4) at tile boundary (t's kh0 = oldest 4)
//   and vmcnt(4) at mid-tile (t's kh1 = oldest 4). vmcnt(0) only at the final tile's mid.
// Barriers: 2 per K-tile. lgkmcnt(0) ONLY at the boundary: pins this wave's ds_reads of
//   buf[cb] before the next tile's staging overwrites that buffer (round-8 race class).
//   Mid barrier has no WAR hazard (staging targets the other dbuf) -> no lgkm drain.
// 32 MFMA per barrier gap (B-frags reused across the two mh phases) -> T5 setprio regime.
template<int OUTF32>
__global__ __launch_bounds__(512, 2) void gemm256(
    const short* __restrict__ A, const short* __restrict__ Bt,
    const float* __restrict__ b0, const float* __restrict__ b1, const float* __restrict__ b2,
    void* __restrict__ Cout, const int N, const int MT) {
  __shared__ alignas(16) short Lds[65536];  // 128KB
  const int tid = threadIdx.x;
  const int l = tid & 63, w = tid >> 6;
  const int lrow = l & 15, lg = l >> 4;
  const int wr = w >> 2, wc = w & 3;

  // bijective XCD swizzle (m204)
  const int nwg = gridDim.x;
  const int qq = nwg >> 3, r8 = nwg & 7;
  const int xcd = blockIdx.x & 7, loc = blockIdx.x >> 3;
  const int wg = (xcd < r8 ? xcd * (qq + 1) : r8 * (qq + 1) + (xcd - r8) * qq) + loc;
  const int mt = wg % MT, nt = wg / MT;
  const int m0 = mt * 256, n0 = nt * 256;

#define KEYR(r) ((((r) & 3)) ^ (((r) >> 2) & 3))

  // staging sources (inverse swizzle): chunk p holds logical slot (p&3)^key(row), row=p>>2
  const short* asrc[2]; const short* bsrc[2];
#pragma unroll
  for (int i = 0; i < 2; ++i) {
    int p = i * 512 + tid;
    int row = p >> 2;
    int lslot = (p & 3) ^ KEYR(row);
    int ra = m0 + row; if (ra > MROWS - 1) ra = MROWS - 1;
    int rb = n0 + row; if (rb > N - 1) rb = N - 1;
    asrc[i] = A + (long)ra * KD + lslot * 8;
    bsrc[i] = Bt + (long)rb * KD + lslot * 8;
  }

#define STAGEA(sb, kh, kt_, i) \
  __builtin_amdgcn_global_load_lds((const AS1 void*)(asrc[i] + (kt_) * 64 + (kh) * 32), \
      (AS3 void*)(&Lds[(sb) * 16384 + (kh) * 8192 + (i * 512 + tid) * 8]), 16, 0, 0)
#define STAGEB(sb, kh, kt_, i) \
  __builtin_amdgcn_global_load_lds((const AS1 void*)(bsrc[i] + (kt_) * 64 + (kh) * 32), \
      (AS3 void*)(&Lds[32768 + (sb) * 16384 + (kh) * 8192 + (i * 512 + tid) * 8]), 16, 0, 0)
#define LDA(dst, base, mi) { const int row_ = wr * 128 + (mi) * 16 + lrow; \
  dst = *(const short8*)&Lds[(base) + row_ * 32 + ((lg ^ KEYR(row_)) << 3)]; }
#define LDB(dst, base, nj) { const int row_ = wc * 64 + (nj) * 16 + lrow; \
  dst = *(const short8*)&Lds[(base) + row_ * 32 + ((lg ^ KEYR(row_)) << 3)]; }
#define MFMA16(a, b, c) __builtin_amdgcn_mfma_f32_16x16x32_bf16(a, b, c, 0, 0, 0)
#define MF16(mb, A0, A1, A2, A3) \
  acc[(mb)+0][0] = MFMA16(A0, bf0, acc[(mb)+0][0]); \
  acc[(mb)+0][1] = MFMA16(A0, bf1, acc[(mb)+0][1]); \
  acc[(mb)+0][2] = MFMA16(A0, bf2, acc[(mb)+0][2]); \
  acc[(mb)+0][3] = MFMA16(A0, bf3, acc[(mb)+0][3]); \
  acc[(mb)+1][0] = MFMA16(A1, bf0, acc[(mb)+1][0]); \
  acc[(mb)+1][1] = MFMA16(A1, bf1, acc[(mb)+1][1]); \
  acc[(mb)+1][2] = MFMA16(A1, bf2, acc[(mb)+1][2]); \
  acc[(mb)+1][3] = MFMA16(A1, bf3, acc[(mb)+1][3]); \
  acc[(mb)+2][0] = MFMA16(A2, bf0, acc[(mb)+2][0]); \
  acc[(mb)+2][1] = MFMA16(A2, bf1, acc[(mb)+2][1]); \
  acc[(mb)+2][2] = MFMA16(A2, bf2, acc[(mb)+2][2]); \
  acc[(mb)+2][3] = MFMA16(A2, bf3, acc[(mb)+2][3]); \
  acc[(mb)+3][0] = MFMA16(A3, bf0, acc[(mb)+3][0]); \
  acc[(mb)+3][1] = MFMA16(A3, bf1, acc[(mb)+3][1]); \
  acc[(mb)+3][2] = MFMA16(A3, bf2, acc[(mb)+3][2]); \
  acc[(mb)+3][3] = MFMA16(A3, bf3, acc[(mb)+3][3]);

  float4_ acc[8][4];
#pragma unroll
  for (int mi = 0; mi < 8; ++mi)
#pragma unroll
    for (int nj = 0; nj < 4; ++nj) acc[mi][nj] = (float4_)(0.f);

  // prologue: stage tile 0 halves in FIFO order A-kh0, B-kh0, A-kh1, B-kh1
  STAGEA(0, 0, 0, 0); STAGEA(0, 0, 0, 1);
  STAGEB(0, 0, 0, 0); STAGEB(0, 0, 0, 1);
  STAGEA(0, 1, 0, 0); STAGEA(0, 1, 0, 1);
  STAGEB(0, 1, 0, 0); STAGEB(0, 1, 0, 1);
  asm volatile("s_waitcnt vmcnt(4)" ::: "memory");   // tile-0 kh0 landed (oldest 4)
  BARM();

  for (int kt = 0; kt < NT2; ++kt) {
    const int cb = kt & 1, sb = (kt + 1) & 1;
    const bool dost = (kt + 1) < NT2;
    const int aK0 = cb * 16384, aK1 = aK0 + 8192;
    const int bK0 = 32768 + cb * 16384, bK1 = bK0 + 8192;
    short8 af0, af1, af2, af3, bf0, bf1, bf2, bf3;

    // ---- phase 0 (kh0, mh0): stage A-kh0(kt+1) ----
    if (dost) { STAGEA(sb, 0, kt + 1, 0); STAGEA(sb, 0, kt + 1, 1); }
    LDB(bf0, bK0, 0); LDB(bf1, bK0, 1); LDB(bf2, bK0, 2); LDB(bf3, bK0, 3);
    LDA(af0, aK0, 0); LDA(af1, aK0, 1); LDA(af2, aK0, 2); LDA(af3, aK0, 3);
    __builtin_amdgcn_s_setprio(1);
    MF16(0, af0, af1, af2, af3);
    __builtin_amdgcn_s_setprio(0);
    // ---- phase 1 (kh0, mh1): stage B-kh0(kt+1); B-frags reused ----
    if (dost) { STAGEB(sb, 0, kt + 1, 0); STAGEB(sb, 0, kt + 1, 1); }
    LDA(af0, aK0, 4); LDA(af1, aK0, 5); LDA(af2, aK0, 6); LDA(af3, aK0, 7);
    __builtin_amdgcn_s_setprio(1);
    MF16(4, af0, af1, af2, af3);
    __builtin_amdgcn_s_setprio(0);
    // ---- mid: kt's kh1 landed (oldest 4 of 8); no WAR -> no lgkm drain ----
    if (dost) asm volatile("s_waitcnt vmcnt(4)" ::: "memory");
    else      asm volatile("s_waitcnt vmcnt(0)" ::: "memory");
    BARM();
    // ---- phase 2 (kh1, mh0): stage A-kh1(kt+1) ----
    if (dost) { STAGEA(sb, 1, kt + 1, 0); STAGEA(sb, 1, kt + 1, 1); }
    LDB(bf0, bK1, 0); LDB(bf1, bK1, 1); LDB(bf2, bK1, 2); LDB(bf3, bK1, 3);
    LDA(af0, aK1, 0); LDA(af1, aK1, 1); LDA(af2, aK1, 2); LDA(af3, aK1, 3);
    __builtin_amdgcn_s_setprio(1);
    MF16(0, af0, af1, af2, af3);
    __builtin_amdgcn_s_setprio(0);
    // ---- phase 3 (kh1, mh1): stage B-kh1(kt+1) ----
    if (dost) { STAGEB(sb, 1, kt + 1, 0); STAGEB(sb, 1, kt + 1, 1); }
    LDA(af0, aK1, 4); LDA(af1, aK1, 5); LDA(af2, aK1, 6); LDA(af3, aK1, 7);
    __builtin_amdgcn_s_setprio(1);
    MF16(4, af0, af1, af2, af3);
    __builtin_amdgcn_s_setprio(0);
    // ---- boundary: drain my ds_reads of buf[cb] (next tile stages into it), then
    //      (kt+1)'s kh0 landed (oldest 4 of 8), one barrier ----
    asm volatile("s_waitcnt lgkmcnt(0)" ::: "memory");
    asm volatile("s_waitcnt vmcnt(4)" ::: "memory");
    BARM();
  }

  // epilogue: 16x16 C layout row = lg*4 + r, col = lrow
  float bias[4];
#pragma unroll
  for (int nj = 0; nj < 4; ++nj) {
    int cn = n0 + wc * 64 + nj * 16 + lrow;
    float bv_ = 0.f;
    if (cn < N) bv_ = (N == HDIM) ? b0[cn]
                                  : (cn < HDIM ? b0[cn] : (cn < 2 * HDIM ? b1[cn - HDIM] : b2[cn - 2 * HDIM]));
    bias[nj] = bv_;
  }
#pragma unroll
  for (int mi = 0; mi < 8; ++mi)
#pragma unroll
    for (int r = 0; r < 4; ++r) {
      int m = m0 + wr * 128 + mi * 16 + lg * 4 + r;
      if (m >= MROWS) continue;
#pragma unroll
      for (int nj = 0; nj < 4; ++nj) {
        int cn = n0 + wc * 64 + nj * 16 + lrow;
        if (cn >= N) continue;
        float v = acc[mi][nj][r] + bias[nj];
        if (OUTF32) ((float*)Cout)[(long)m * N + cn] = v;
        else        ((short*)Cout)[(long)m * N + cn] = f2bf(v);
      }
    }
#undef STAGEA
#undef STAGEB
#undef LDA
#undef LDB
#undef MFMA16
#undef MF16
#undef KEYR
}

// ---------------- rotary on Q only (vectorized short8; K handled in fragpack) ----------------
__global__ __launch_bounds__(256) void rotary_q(short* __restrict__ QKV,
                                                const int* __restrict__ rowsp,
                                                const int* __restrict__ colsp) {
  int idx = blockIdx.x * 256 + threadIdx.x;
  if (idx >= MROWS * NH * 4) return;
  const int qt = idx & 3;
  const int hm = idx >> 2;
  const int h = hm % NH, m = hm / NH;
  const int s = m % SEQ;
  const int cols = colsp[0], rws = rowsp[0];
  const int off = (SEQ != rws * cols) ? 1 : 0;
  int gid = s - off; if (gid < 0) gid = 0;
  const float frow = (float)(gid / cols), fcol = (float)(gid % cols);
  union { short sh[24]; short8 v[3]; } u;
  short* p = QKV + (long)m * N_QKV + h * DH + qt * 24;
  u.v[0] = *(short8*)p; u.v[1] = *(short8*)(p + 8); u.v[2] = *(short8*)(p + 16);
#pragma unroll
  for (int t = 0; t < 8; ++t) {
    int j = qt * 8 + t;
    float invf = exp2f((float)(3 * j) * (-13.287712379549449f / 192.0f));
    float st, ct, sp, cp;
    __sincosf(frow * invf, &st, &ct);
    __sincosf(fcol * invf, &sp, &cp);
    float x0 = bf2f(u.sh[3 * t]), x1 = bf2f(u.sh[3 * t + 1]), x2 = bf2f(u.sh[3 * t + 2]);
    u.sh[3 * t]     = f2bf( cp * x0 + sp * st * x1 + sp * ct * x2);
    u.sh[3 * t + 1] = f2bf( ct * x1 - st * x2);
    u.sh[3 * t + 2] = f2bf(-sp * x0 + cp * st * x1 + cp * ct * x2);
  }
  *(short8*)p = u.v[0]; *(short8*)(p + 8) = u.v[1]; *(short8*)(p + 16) = u.v[2];
}

// ---------------- fragment prepack (+K rotary fused) ----------------
__global__ __launch_bounds__(256) void fragpack(const short* __restrict__ QKV,
                                                short* __restrict__ Kf,
                                                short* __restrict__ Vf,
                                                const int* __restrict__ rowsp,
                                                const int* __restrict__ colsp) {
  __shared__ short L[64 * 96];  // [kv=2][row 32][96]
  const int t = blockIdx.x, bh = blockIdx.y;
  const int b = bh / NH, h = bh % NH;
  const int tid = threadIdx.x;
#pragma unroll
  for (int i = 0; i < 3; ++i) {
    int cc = i * 256 + tid;
    int kv = cc / 384;
    int rm = cc % 384;
    int r = rm / 12, m = rm % 12;
    int s = t * 32 + r; if (s > SEQ - 1) s = SEQ - 1;
    const short* src = QKV + (long)(b * SEQ + s) * N_QKV + (kv ? 2 * HDIM : HDIM) + h * DH + m * 8;
    *(short8*)&L[cc * 8] = *(const short8*)src;
  }
  __syncthreads();
  {
    const int cols = colsp[0], rws = rowsp[0];
    const int off = (SEQ != rws * cols) ? 1 : 0;
#pragma unroll
    for (int i = 0; i < 4; ++i) {
      int idx2 = i * 256 + tid;      // 1024 = 32 rows x 32 triplets
      int r = idx2 >> 5, j = idx2 & 31;
      int s = t * 32 + r; if (s > SEQ - 1) s = SEQ - 1;
      int gid = s - off; if (gid < 0) gid = 0;
      float invf = exp2f((float)(3 * j) * (-13.287712379549449f / 192.0f));
      float st, ct, sp, cp;
      __sincosf((float)(gid / cols) * invf, &st, &ct);
      __sincosf((float)(gid % cols) * invf, &sp, &cp);
      short* pp = &L[r * 96 + 3 * j];
      float x0 = bf2f(pp[0]), x1 = bf2f(pp[1]), x2 = bf2f(pp[2]);
      pp[0] = f2bf( cp * x0 + sp * st * x1 + sp * ct * x2);
      pp[1] = f2bf( ct * x1 - st * x2);
      pp[2] = f2bf(-sp * x0 + cp * st * x1 + cp * ct * x2);
    }
  }
  __syncthreads();
#pragma unroll
  for (int i = 0; i < 3; ++i) {
    int oc = i * 256 + tid;
    if (oc < 384) {
      int c = oc / 64, ll = oc & 63;
      int qi = ll & 31, hi = ll >> 5;
      short8 v = *(const short8*)&L[qi * 96 + c * 16 + hi * 8];
      *(short8*)(Kf + (((long)(bh * 33 + t) * 6 + c) * 64 + ll) * 8) = v;
    } else {
      int oc2 = oc - 384;
      int d = oc2 / 128, sl = (oc2 / 64) & 1, ll = oc2 & 63;
      int qi = ll & 31, hi = ll >> 5;
      short8 v;
#pragma unroll
      for (int j = 0; j < 8; ++j)
        v[j] = L[32 * 96 + (sl * 16 + hi * 8 + j) * 96 + d * 32 + qi];
      *(short8*)(Vf + ((((long)(bh * 33 + t) * 3 + d) * 2 + sl) * 64 + ll) * 8) = v;
    }
  }
}

// ---------------- flash attention, swapped-operand 32x32, prepacked K/V ----------------
__global__ __launch_bounds__(128, 3) void attn_kernel(const short* __restrict__ QKV,
                                                      const short* __restrict__ Kf,
                                                      const short* __restrict__ Vf,
                                                      short* __restrict__ CTX) {
  const int tid = threadIdx.x;
  const int l = tid & 63, w = tid >> 6;
  const int qi = l & 31, hi = l >> 5;
  const int bid = blockIdx.x;
  const int xcd = bid & 7, jj = bid >> 3;
  const int bh = xcd * 12 + jj / 17;
  const int qb = jj % 17;
  const int b = bh / NH, h = bh % NH;
  const int s = qb * 64 + w * 32 + qi;
  const int sq = s > SEQ - 1 ? SEQ - 1 : s;

  const float scale = 0.1020620726159658f;  // 96^-0.5
  const short* Qr = QKV + (long)(b * SEQ + sq) * N_QKV + h * DH;
  short8 qf[6];
#pragma unroll
  for (int c = 0; c < 6; ++c) {
    short8 v = *(const short8*)(Qr + c * 16 + hi * 8);
#pragma unroll
    for (int j = 0; j < 8; ++j) v[j] = f2bf(bf2f(v[j]) * scale);
    qf[c] = v;
  }

  const short* Kb = Kf + (long)bh * 33 * 6 * 64 * 8;
  const short* Vb = Vf + (long)bh * 33 * 6 * 64 * 8;

  f32x16 ctxv[3];
#pragma unroll
  for (int d = 0; d < 3; ++d) ctxv[d] = (f32x16)(0.f);
  float m_ = -1e30f, l_ = 0.f;

  for (int t = 0; t < 33; ++t) {
    f32x16 S = (f32x16)(0.f);
#pragma unroll
    for (int c = 0; c < 6; ++c) {
      short8 kf = *(const short8*)(Kb + (((long)t * 6 + c) * 64 + l) * 8);
      S = __builtin_amdgcn_mfma_f32_32x32x16_bf16(kf, qf[c], S, 0, 0, 0);
    }
    if (t == 32) {
      S[0] = hi ? -1e30f : S[0];
#pragma unroll
      for (int r = 1; r < 16; ++r) S[r] = -1e30f;
    }
    float tm = S[0];
#pragma unroll
    for (int r = 1; r < 16; ++r) tm = fmaxf(tm, S[r]);
    tm = fmaxf(tm, __shfl_xor(tm, 32));
    if (!__all(tm - m_ <= 8.f)) {
      float mn = fmaxf(m_, tm);
      float alpha = __expf(m_ - mn);
      m_ = mn;
      l_ *= alpha;
#pragma unroll
      for (int d = 0; d < 3; ++d)
#pragma unroll
        for (int r = 0; r < 16; ++r) ctxv[d][r] *= alpha;
    }
    float ts = 0.f;
#pragma unroll
    for (int r = 0; r < 16; ++r) { float p = __expf(S[r] - m_); S[r] = p; ts += p; }
    ts += __shfl_xor(ts, 32);
    l_ += ts;

    unsigned pk_[8];
#pragma unroll
    for (int j = 0; j < 8; ++j)
      pk_[j] = (unsigned)(unsigned short)f2bf(S[2 * j]) |
               ((unsigned)(unsigned short)f2bf(S[2 * j + 1]) << 16);
    unsigned s0 = hi ? pk_[0] : pk_[2];
    unsigned s1 = hi ? pk_[1] : pk_[3];
    unsigned s2 = hi ? pk_[4] : pk_[6];
    unsigned s3 = hi ? pk_[5] : pk_[7];
    unsigned r0 = __shfl_xor(s0, 32);
    unsigned r1 = __shfl_xor(s1, 32);
    unsigned r2 = __shfl_xor(s2, 32);
    unsigned r3 = __shfl_xor(s3, 32);
    union PF { unsigned u[4]; short8 s8; } f0, f1;
    f0.u[0] = hi ? r0 : pk_[0];
    f0.u[1] = hi ? r1 : pk_[1];
    f0.u[2] = hi ? pk_[2] : r0;
    f0.u[3] = hi ? pk_[3] : r1;
    f1.u[0] = hi ? r2 : pk_[4];
    f1.u[1] = hi ? r3 : pk_[5];
    f1.u[2] = hi ? pk_[6] : r2;
    f1.u[3] = hi ? pk_[7] : r3;

#pragma unroll
    for (int d = 0; d < 3; ++d) {
      const short* Vr = Vb + (((long)t * 3 + d) * 2 * 64) * 8;
      short8 vf0 = *(const short8*)(Vr + l * 8);
      ctxv[d] = __builtin_amdgcn_mfma_f32_32x32x16_bf16(vf0, f0.s8, ctxv[d], 0, 0, 0);
      short8 vf1 = *(const short8*)(Vr + (64 + l) * 8);
      ctxv[d] = __builtin_amdgcn_mfma_f32_32x32x16_bf16(vf1, f1.s8, ctxv[d], 0, 0, 0);
    }
  }

  float invl = 1.f / l_;
  if (s <= SEQ - 1) {
    short* Cr = CTX + (long)(b * SEQ + s) * HDIM + h * DH;
#pragma unroll
    for (int d = 0; d < 3; ++d)
#pragma unroll
      for (int g = 0; g < 4; ++g) {
        short4_ o;
#pragma unroll
        for (int r = 0; r < 4; ++r) o[r] = f2bf(ctxv[d][4 * g + r] * invl);
        *(short4_*)(Cr + d * 32 + 8 * g + 4 * hi) = o;
      }
  }
}

extern "C" void kernel_launch(void* const* d_in, const int* in_sizes, int n_in,
                              void* d_out, int out_size, void* d_ws, size_t ws_size,
                              hipStream_t stream) {
  const float* hs = (const float*)d_in[0];
  const float* Wq = (const float*)d_in[1];
  const float* bq = (const float*)d_in[2];
  const float* Wk = (const float*)d_in[3];
  const float* bk = (const float*)d_in[4];
  const float* Wv = (const float*)d_in[5];
  const float* bv = (const float*)d_in[6];
  const float* Wo = (const float*)d_in[7];
  const float* bo = (const float*)d_in[8];
  const int* rows = (const int*)d_in[9];
  const int* cols = (const int*)d_in[10];
  float* out = (float*)d_out;

  char* ws = (char*)d_ws;
  short* X   = (short*)(ws);               // 8200*1152*2      = 18,892,800
  short* Wt  = (short*)(ws + 18892800);    // 3456*1152*2      =  7,962,624
  short* Wot = (short*)(ws + 26855424);    // 1152*1152*2      =  2,654,208
  short* QKV = (short*)(ws + 29509632);    // 8200*3456*2      = 56,678,400
  short* Vf  = (short*)(ws + 86188032);    // 96*33*6*64*16B   = 19,464,192
  short* CTX = (short*)(ws + 105652224);   // 8200*1152*2      = 18,892,800  (end 124,545,024)
  short* Kf  = (short*)(ws);               // 19,464,192 — reuses X+Wt region (dead after gemm<0>)

  convx<<<9225, 256, 0, stream>>>(hs, X);
  convw_t<<<dim3(18, 18, 3), 256, 0, stream>>>(Wq, Wk, Wv, Wt);
  convw_t<<<dim3(18, 18, 1), 256, 0, stream>>>(Wo, Wo, Wo, Wot);
  gemm256<0><<<462, 512, 0, stream>>>(X, Wt, bq, bk, bv, QKV, N_QKV, 33);   // 33 M x 14 N tiles
  rotary_q<<<1538, 256, 0, stream>>>(QKV, rows, cols);
  fragpack<<<dim3(33, 96), 256, 0, stream>>>(QKV, Kf, Vf, rows, cols);
  attn_kernel<<<1632, 128, 0, stream>>>(QKV, Kf, Vf, CTX);
  gemm256<1><<<165, 512, 0, stream>>>(CTX, Wot, bo, bo, bo, out, HDIM, 33); // 33 M x 5 N tiles
}

// Round 11
// 275.319 us; speedup vs baseline: 1.0498x; 1.0140x over previous
//
#include <hip/hip_runtime.h>
#include <stdint.h>

#define BATCH 8
#define SEQ   1025
#define HDIM  1152
#define NH    12
#define DH    96
#define MROWS (BATCH*SEQ)   // 8200
#define N_QKV (3*HDIM)      // 3456
#define KD    HDIM          // 1152 (K of both GEMMs)
#define NT2   18            // K-tiles of 64

typedef __attribute__((ext_vector_type(8))) short short8;
typedef __attribute__((ext_vector_type(4))) short short4_;
typedef __attribute__((ext_vector_type(4))) float float4_;
typedef __attribute__((ext_vector_type(16))) float f32x16;

#define AS1 __attribute__((address_space(1)))
#define AS3 __attribute__((address_space(3)))
#define BARM() do { asm volatile("" ::: "memory"); __builtin_amdgcn_s_barrier(); asm volatile("" ::: "memory"); } while (0)
#define LGKM0() do { asm volatile("s_waitcnt lgkmcnt(0)" ::: "memory"); __builtin_amdgcn_sched_barrier(0); } while (0)

__device__ inline float bf2f(short s) {
  union { unsigned u; float f; } x; x.u = ((unsigned)(unsigned short)s) << 16; return x.f;
}
__device__ inline short f2bf(float f) {
  union { float f; unsigned u; } x; x.f = f;
  unsigned r = (x.u + 0x7fffu + ((x.u >> 16) & 1u)) >> 16;
  return (short)r;
}

// ---------------- converts ----------------
__global__ __launch_bounds__(256) void convx(const float* __restrict__ hs, short* __restrict__ X) {
  int i = blockIdx.x * 256 + threadIdx.x;  // exactly 2361600 threads
  float4_ v = ((const float4_*)hs)[i];
  short4_ o;
  o[0] = f2bf(v[0]); o[1] = f2bf(v[1]); o[2] = f2bf(v[2]); o[3] = f2bf(v[3]);
  ((short4_*)X)[i] = o;
}

// tiled transpose-cast: Wt[z*1152 + n][k] = W_z[k][n]
__global__ __launch_bounds__(256) void convw_t(const float* __restrict__ W0,
                                               const float* __restrict__ W1,
                                               const float* __restrict__ W2,
                                               short* __restrict__ Wt) {
  __shared__ float T[64][65];
  const int z = blockIdx.z;
  const float* W = z == 0 ? W0 : (z == 1 ? W1 : W2);
  const int n0 = blockIdx.x * 64, k0 = blockIdx.y * 64;
  const int tid = threadIdx.x;
  const int r = tid >> 2, cq = (tid & 3) * 16;
#pragma unroll
  for (int u = 0; u < 4; ++u) {
    float4_ v = *(const float4_*)&W[(long)(k0 + r) * HDIM + n0 + cq + u * 4];
    T[r][cq + u * 4 + 0] = v[0]; T[r][cq + u * 4 + 1] = v[1];
    T[r][cq + u * 4 + 2] = v[2]; T[r][cq + u * 4 + 3] = v[3];
  }
  __syncthreads();
  const int n = tid >> 2, kq = (tid & 3) * 16;
  short out[16];
#pragma unroll
  for (int u = 0; u < 16; ++u) out[u] = f2bf(T[kq + u][n]);
  short* dst = Wt + (long)(z * HDIM + n0 + n) * KD + k0 + kq;
  *(short8*)dst = *(short8*)&out[0];
  *(short8*)(dst + 8) = *(short8*)&out[8];
}

// ---------------- GEMM 256x256, 8-wave, BK=64, m201-faithful 4-phase/K-tile ----------------
// LDS 128KB: A sub-buffers (dbuf sb, khalf kh) = [256 rows][32 k] bf16 (16KB) at
// sb*16384 + kh*8192 shorts; B same at +32768 shorts.
// Swizzle (round-6 verified, 0 conflicts): row = 64B; line = row>>1 (128B, 8x16B slots);
//   phys_slot = ((row&1)*4 + lg) ^ ((row>>1)&7)  — involution within the line.
//   Staging inverse on per-lane SOURCE (gload_lds writes linearly, Rule 21):
//   p -> wl=(p&7)^((p>>3)&7); row=(p>>3)*2+(wl>>2); kc=(wl&3)*8.
// Phase template (m201): { ds_reads ; stage 1 half-tile } -> s_barrier -> lgkmcnt(0)+
//   sched_barrier(0) -> setprio(1) + 16 MFMA + setprio(0) -> [counted vmcnt] -> s_barrier.
// 4 phases per K-tile: (kh0,mh0) (kh0,mh1) (kh1,mh0) (kh1,mh1); stages A-kh0, B-kh0,
//   A-kh1, B-kh1 of tile t+1 in that FIFO order.
// Counted waits (never 0 mid-loop): vmcnt(4) at phase-2 close (kt's kh1 = oldest 4 of 8)
//   and vmcnt(4) at phase-4 close (kt+1's kh0 = oldest 4 of 8). Tail drains explicitly.
// Race-safety: each phase's lgkmcnt(0) precedes its closing barrier in asm program order,
//   so all ds_reads of buf[cb] drain before tile t+1 stages into it (round-8 race class).
template<int OUTF32>
__global__ __launch_bounds__(512, 2) void gemm256(
    const short* __restrict__ A, const short* __restrict__ Bt,
    const float* __restrict__ b0, const float* __restrict__ b1, const float* __restrict__ b2,
    void* __restrict__ Cout, const int N, const int MT) {
  __shared__ alignas(16) short Lds[65536];  // 128KB
  const int tid = threadIdx.x;
  const int l = tid & 63, w = tid >> 6;
  const int lrow = l & 15, lg = l >> 4;
  const int wr = w >> 2, wc = w & 3;

  // bijective XCD swizzle (m204)
  const int nwg = gridDim.x;
  const int qq = nwg >> 3, r8 = nwg & 7;
  const int xcd = blockIdx.x & 7, loc = blockIdx.x >> 3;
  const int wg = (xcd < r8 ? xcd * (qq + 1) : r8 * (qq + 1) + (xcd - r8) * qq) + loc;
  const int mt = wg % MT, nt = wg / MT;
  const int m0 = mt * 256, n0 = nt * 256;

  // staging sources (inverse swizzle)
  const short* asrc[2]; const short* bsrc[2];
#pragma unroll
  for (int i = 0; i < 2; ++i) {
    int p = i * 512 + tid;
    int wl = (p & 7) ^ ((p >> 3) & 7);
    int row = ((p >> 3) << 1) | (wl >> 2);
    int kc = (wl & 3) * 8;
    int ra = m0 + row; if (ra > MROWS - 1) ra = MROWS - 1;
    int rb = n0 + row; if (rb > N - 1) rb = N - 1;
    asrc[i] = A + (long)ra * KD + kc;
    bsrc[i] = Bt + (long)rb * KD + kc;
  }

#define STAGEA(sb, kh, kt_, i) \
  __builtin_amdgcn_global_load_lds((const AS1 void*)(asrc[i] + (kt_) * 64 + (kh) * 32), \
      (AS3 void*)(&Lds[(sb) * 16384 + (kh) * 8192 + (i * 512 + tid) * 8]), 16, 0, 0)
#define STAGEB(sb, kh, kt_, i) \
  __builtin_amdgcn_global_load_lds((const AS1 void*)(bsrc[i] + (kt_) * 64 + (kh) * 32), \
      (AS3 void*)(&Lds[32768 + (sb) * 16384 + (kh) * 8192 + (i * 512 + tid) * 8]), 16, 0, 0)
#define LDA(dst, base, mi) { const int row_ = wr * 128 + (mi) * 16 + lrow; \
  dst = *(const short8*)&Lds[(base) + ((row_ >> 1) << 6) + \
      (((((row_ & 1) << 2) + lg) ^ ((row_ >> 1) & 7)) << 3)]; }
#define LDB(dst, base, nj) { const int row_ = wc * 64 + (nj) * 16 + lrow; \
  dst = *(const short8*)&Lds[(base) + ((row_ >> 1) << 6) + \
      (((((row_ & 1) << 2) + lg) ^ ((row_ >> 1) & 7)) << 3)]; }
#define MFMA16(a, b, c) __builtin_amdgcn_mfma_f32_16x16x32_bf16(a, b, c, 0, 0, 0)
#define MF16(mb, A0, A1, A2, A3) \
  acc[(mb)+0][0] = MFMA16(A0, bf0, acc[(mb)+0][0]); \
  acc[(mb)+0][1] = MFMA16(A0, bf1, acc[(mb)+0][1]); \
  acc[(mb)+0][2] = MFMA16(A0, bf2, acc[(mb)+0][2]); \
  acc[(mb)+0][3] = MFMA16(A0, bf3, acc[(mb)+0][3]); \
  acc[(mb)+1][0] = MFMA16(A1, bf0, acc[(mb)+1][0]); \
  acc[(mb)+1][1] = MFMA16(A1, bf1, acc[(mb)+1][1]); \
  acc[(mb)+1][2] = MFMA16(A1, bf2, acc[(mb)+1][2]); \
  acc[(mb)+1][3] = MFMA16(A1, bf3, acc[(mb)+1][3]); \
  acc[(mb)+2][0] = MFMA16(A2, bf0, acc[(mb)+2][0]); \
  acc[(mb)+2][1] = MFMA16(A2, bf1, acc[(mb)+2][1]); \
  acc[(mb)+2][2] = MFMA16(A2, bf2, acc[(mb)+2][2]); \
  acc[(mb)+2][3] = MFMA16(A2, bf3, acc[(mb)+2][3]); \
  acc[(mb)+3][0] = MFMA16(A3, bf0, acc[(mb)+3][0]); \
  acc[(mb)+3][1] = MFMA16(A3, bf1, acc[(mb)+3][1]); \
  acc[(mb)+3][2] = MFMA16(A3, bf2, acc[(mb)+3][2]); \
  acc[(mb)+3][3] = MFMA16(A3, bf3, acc[(mb)+3][3]);

  float4_ acc[8][4];
#pragma unroll
  for (int mi = 0; mi < 8; ++mi)
#pragma unroll
    for (int nj = 0; nj < 4; ++nj) acc[mi][nj] = (float4_)(0.f);

  // prologue: stage tile 0 in FIFO order A-kh0, B-kh0, A-kh1, B-kh1 (8 loads)
  STAGEA(0, 0, 0, 0); STAGEA(0, 0, 0, 1);
  STAGEB(0, 0, 0, 0); STAGEB(0, 0, 0, 1);
  STAGEA(0, 1, 0, 0); STAGEA(0, 1, 0, 1);
  STAGEB(0, 1, 0, 0); STAGEB(0, 1, 0, 1);
  asm volatile("s_waitcnt vmcnt(4)" ::: "memory");   // tile-0 kh0 landed (oldest 4)
  BARM();

  for (int kt = 0; kt < NT2; ++kt) {
    const int cb = kt & 1, sb = (kt + 1) & 1;
    const bool dost = (kt + 1) < NT2;
    const int aK0 = cb * 16384, aK1 = aK0 + 8192;
    const int bK0 = 32768 + cb * 16384, bK1 = bK0 + 8192;
    short8 af0, af1, af2, af3, bf0, bf1, bf2, bf3;

    // ---- phase 1 (kh0, mh0): 12 ds_reads; stage A-kh0(kt+1) ----
    LDB(bf0, bK0, 0); LDB(bf1, bK0, 1); LDB(bf2, bK0, 2); LDB(bf3, bK0, 3);
    LDA(af0, aK0, 0); LDA(af1, aK0, 1); LDA(af2, aK0, 2); LDA(af3, aK0, 3);
    if (dost) { STAGEA(sb, 0, kt + 1, 0); STAGEA(sb, 0, kt + 1, 1); }
    BARM();
    LGKM0();
    __builtin_amdgcn_s_setprio(1);
    MF16(0, af0, af1, af2, af3);
    __builtin_amdgcn_s_setprio(0);
    BARM();
    // ---- phase 2 (kh0, mh1): 4 ds_reads; stage B-kh0(kt+1); mid counted vmcnt ----
    LDA(af0, aK0, 4); LDA(af1, aK0, 5); LDA(af2, aK0, 6); LDA(af3, aK0, 7);
    if (dost) { STAGEB(sb, 0, kt + 1, 0); STAGEB(sb, 0, kt + 1, 1); }
    BARM();
    LGKM0();
    __builtin_amdgcn_s_setprio(1);
    MF16(4, af0, af1, af2, af3);
    __builtin_amdgcn_s_setprio(0);
    if (dost) asm volatile("s_waitcnt vmcnt(4)" ::: "memory");  // kt's kh1 landed
    else      asm volatile("s_waitcnt vmcnt(0)" ::: "memory");  // tail drain
    BARM();
    // ---- phase 3 (kh1, mh0): 12 ds_reads; stage A-kh1(kt+1) ----
    LDB(bf0, bK1, 0); LDB(bf1, bK1, 1); LDB(bf2, bK1, 2); LDB(bf3, bK1, 3);
    LDA(af0, aK1, 0); LDA(af1, aK1, 1); LDA(af2, aK1, 2); LDA(af3, aK1, 3);
    if (dost) { STAGEA(sb, 1, kt + 1, 0); STAGEA(sb, 1, kt + 1, 1); }
    BARM();
    LGKM0();
    __builtin_amdgcn_s_setprio(1);
    MF16(0, af0, af1, af2, af3);
    __builtin_amdgcn_s_setprio(0);
    BARM();
    // ---- phase 4 (kh1, mh1): 4 ds_reads; stage B-kh1(kt+1); boundary counted vmcnt ----
    LDA(af0, aK1, 4); LDA(af1, aK1, 5); LDA(af2, aK1, 6); LDA(af3, aK1, 7);
    if (dost) { STAGEB(sb, 1, kt + 1, 0); STAGEB(sb, 1, kt + 1, 1); }
    BARM();
    LGKM0();
    __builtin_amdgcn_s_setprio(1);
    MF16(4, af0, af1, af2, af3);
    __builtin_amdgcn_s_setprio(0);
    if (dost) asm volatile("s_waitcnt vmcnt(4)" ::: "memory");  // (kt+1)'s kh0 landed
    BARM();
  }

  // epilogue: 16x16 C layout row = lg*4 + r, col = lrow
  float bias[4];
#pragma unroll
  for (int nj = 0; nj < 4; ++nj) {
    int cn = n0 + wc * 64 + nj * 16 + lrow;
    float bv_ = 0.f;
    if (cn < N) bv_ = (N == HDIM) ? b0[cn]
                                  : (cn < HDIM ? b0[cn] : (cn < 2 * HDIM ? b1[cn - HDIM] : b2[cn - 2 * HDIM]));
    bias[nj] = bv_;
  }
#pragma unroll
  for (int mi = 0; mi < 8; ++mi)
#pragma unroll
    for (int r = 0; r < 4; ++r) {
      int m = m0 + wr * 128 + mi * 16 + lg * 4 + r;
      if (m >= MROWS) continue;
#pragma unroll
      for (int nj = 0; nj < 4; ++nj) {
        int cn = n0 + wc * 64 + nj * 16 + lrow;
        if (cn >= N) continue;
        float v = acc[mi][nj][r] + bias[nj];
        if (OUTF32) ((float*)Cout)[(long)m * N + cn] = v;
        else        ((short*)Cout)[(long)m * N + cn] = f2bf(v);
      }
    }
#undef STAGEA
#undef STAGEB
#undef LDA
#undef LDB
#undef MFMA16
#undef MF16
}

// ---------------- rotary on Q only (vectorized short8; K handled in fragpack) ----------------
__global__ __launch_bounds__(256) void rotary_q(short* __restrict__ QKV,
                                                const int* __restrict__ rowsp,
                                                const int* __restrict__ colsp) {
  int idx = blockIdx.x * 256 + threadIdx.x;
  if (idx >= MROWS * NH * 4) return;
  const int qt = idx & 3;
  const int hm = idx >> 2;
  const int h = hm % NH, m = hm / NH;
  const int s = m % SEQ;
  const int cols = colsp[0], rws = rowsp[0];
  const int off = (SEQ != rws * cols) ? 1 : 0;
  int gid = s - off; if (gid < 0) gid = 0;
  const float frow = (float)(gid / cols), fcol = (float)(gid % cols);
  union { short sh[24]; short8 v[3]; } u;
  short* p = QKV + (long)m * N_QKV + h * DH + qt * 24;
  u.v[0] = *(short8*)p; u.v[1] = *(short8*)(p + 8); u.v[2] = *(short8*)(p + 16);
#pragma unroll
  for (int t = 0; t < 8; ++t) {
    int j = qt * 8 + t;
    float invf = exp2f((float)(3 * j) * (-13.287712379549449f / 192.0f));
    float st, ct, sp, cp;
    __sincosf(frow * invf, &st, &ct);
    __sincosf(fcol * invf, &sp, &cp);
    float x0 = bf2f(u.sh[3 * t]), x1 = bf2f(u.sh[3 * t + 1]), x2 = bf2f(u.sh[3 * t + 2]);
    u.sh[3 * t]     = f2bf( cp * x0 + sp * st * x1 + sp * ct * x2);
    u.sh[3 * t + 1] = f2bf( ct * x1 - st * x2);
    u.sh[3 * t + 2] = f2bf(-sp * x0 + cp * st * x1 + cp * ct * x2);
  }
  *(short8*)p = u.v[0]; *(short8*)(p + 8) = u.v[1]; *(short8*)(p + 16) = u.v[2];
}

// ---------------- fragment prepack (+K rotary fused) ----------------
__global__ __launch_bounds__(256) void fragpack(const short* __restrict__ QKV,
                                                short* __restrict__ Kf,
                                                short* __restrict__ Vf,
                                                const int* __restrict__ rowsp,
                                                const int* __restrict__ colsp) {
  __shared__ short L[64 * 96];  // [kv=2][row 32][96]
  const int t = blockIdx.x, bh = blockIdx.y;
  const int b = bh / NH, h = bh % NH;
  const int tid = threadIdx.x;
#pragma unroll
  for (int i = 0; i < 3; ++i) {
    int cc = i * 256 + tid;
    int kv = cc / 384;
    int rm = cc % 384;
    int r = rm / 12, m = rm % 12;
    int s = t * 32 + r; if (s > SEQ - 1) s = SEQ - 1;
    const short* src = QKV + (long)(b * SEQ + s) * N_QKV + (kv ? 2 * HDIM : HDIM) + h * DH + m * 8;
    *(short8*)&L[cc * 8] = *(const short8*)src;
  }
  __syncthreads();
  {
    const int cols = colsp[0], rws = rowsp[0];
    const int off = (SEQ != rws * cols) ? 1 : 0;
#pragma unroll
    for (int i = 0; i < 4; ++i) {
      int idx2 = i * 256 + tid;      // 1024 = 32 rows x 32 triplets
      int r = idx2 >> 5, j = idx2 & 31;
      int s = t * 32 + r; if (s > SEQ - 1) s = SEQ - 1;
      int gid = s - off; if (gid < 0) gid = 0;
      float invf = exp2f((float)(3 * j) * (-13.287712379549449f / 192.0f));
      float st, ct, sp, cp;
      __sincosf((float)(gid / cols) * invf, &st, &ct);
      __sincosf((float)(gid % cols) * invf, &sp, &cp);
      short* pp = &L[r * 96 + 3 * j];
      float x0 = bf2f(pp[0]), x1 = bf2f(pp[1]), x2 = bf2f(pp[2]);
      pp[0] = f2bf( cp * x0 + sp * st * x1 + sp * ct * x2);
      pp[1] = f2bf( ct * x1 - st * x2);
      pp[2] = f2bf(-sp * x0 + cp * st * x1 + cp * ct * x2);
    }
  }
  __syncthreads();
#pragma unroll
  for (int i = 0; i < 3; ++i) {
    int oc = i * 256 + tid;
    if (oc < 384) {
      int c = oc / 64, ll = oc & 63;
      int qi = ll & 31, hi = ll >> 5;
      short8 v = *(const short8*)&L[qi * 96 + c * 16 + hi * 8];
      *(short8*)(Kf + (((long)(bh * 33 + t) * 6 + c) * 64 + ll) * 8) = v;
    } else {
      int oc2 = oc - 384;
      int d = oc2 / 128, sl = (oc2 / 64) & 1, ll = oc2 & 63;
      int qi = ll & 31, hi = ll >> 5;
      short8 v;
#pragma unroll
      for (int j = 0; j < 8; ++j)
        v[j] = L[32 * 96 + (sl * 16 + hi * 8 + j) * 96 + d * 32 + qi];
      *(short8*)(Vf + ((((long)(bh * 33 + t) * 3 + d) * 2 + sl) * 64 + ll) * 8) = v;
    }
  }
}

// ---------------- flash attention, swapped-operand 32x32, prepacked K/V ----------------
__global__ __launch_bounds__(128, 3) void attn_kernel(const short* __restrict__ QKV,
                                                      const short* __restrict__ Kf,
                                                      const short* __restrict__ Vf,
                                                      short* __restrict__ CTX) {
  const int tid = threadIdx.x;
  const int l = tid & 63, w = tid >> 6;
  const int qi = l & 31, hi = l >> 5;
  const int bid = blockIdx.x;
  const int xcd = bid & 7, jj = bid >> 3;
  const int bh = xcd * 12 + jj / 17;
  const int qb = jj % 17;
  const int b = bh / NH, h = bh % NH;
  const int s = qb * 64 + w * 32 + qi;
  const int sq = s > SEQ - 1 ? SEQ - 1 : s;

  const float scale = 0.1020620726159658f;  // 96^-0.5
  const short* Qr = QKV + (long)(b * SEQ + sq) * N_QKV + h * DH;
  short8 qf[6];
#pragma unroll
  for (int c = 0; c < 6; ++c) {
    short8 v = *(const short8*)(Qr + c * 16 + hi * 8);
#pragma unroll
    for (int j = 0; j < 8; ++j) v[j] = f2bf(bf2f(v[j]) * scale);
    qf[c] = v;
  }

  const short* Kb = Kf + (long)bh * 33 * 6 * 64 * 8;
  const short* Vb = Vf + (long)bh * 33 * 6 * 64 * 8;

  f32x16 ctxv[3];
#pragma unroll
  for (int d = 0; d < 3; ++d) ctxv[d] = (f32x16)(0.f);
  float m_ = -1e30f, l_ = 0.f;

  for (int t = 0; t < 33; ++t) {
    f32x16 S = (f32x16)(0.f);
#pragma unroll
    for (int c = 0; c < 6; ++c) {
      short8 kf = *(const short8*)(Kb + (((long)t * 6 + c) * 64 + l) * 8);
      S = __builtin_amdgcn_mfma_f32_32x32x16_bf16(kf, qf[c], S, 0, 0, 0);
    }
    if (t == 32) {
      S[0] = hi ? -1e30f : S[0];
#pragma unroll
      for (int r = 1; r < 16; ++r) S[r] = -1e30f;
    }
    float tm = S[0];
#pragma unroll
    for (int r = 1; r < 16; ++r) tm = fmaxf(tm, S[r]);
    tm = fmaxf(tm, __shfl_xor(tm, 32));
    if (!__all(tm - m_ <= 8.f)) {
      float mn = fmaxf(m_, tm);
      float alpha = __expf(m_ - mn);
      m_ = mn;
      l_ *= alpha;
#pragma unroll
      for (int d = 0; d < 3; ++d)
#pragma unroll
        for (int r = 0; r < 16; ++r) ctxv[d][r] *= alpha;
    }
    float ts = 0.f;
#pragma unroll
    for (int r = 0; r < 16; ++r) { float p = __expf(S[r] - m_); S[r] = p; ts += p; }
    ts += __shfl_xor(ts, 32);
    l_ += ts;

    unsigned pk_[8];
#pragma unroll
    for (int j = 0; j < 8; ++j)
      pk_[j] = (unsigned)(unsigned short)f2bf(S[2 * j]) |
               ((unsigned)(unsigned short)f2bf(S[2 * j + 1]) << 16);
    unsigned s0 = hi ? pk_[0] : pk_[2];
    unsigned s1 = hi ? pk_[1] : pk_[3];
    unsigned s2 = hi ? pk_[4] : pk_[6];
    unsigned s3 = hi ? pk_[5] : pk_[7];
    unsigned r0 = __shfl_xor(s0, 32);
    unsigned r1 = __shfl_xor(s1, 32);
    unsigned r2 = __shfl_xor(s2, 32);
    unsigned r3 = __shfl_xor(s3, 32);
    union PF { unsigned u[4]; short8 s8; } f0, f1;
    f0.u[0] = hi ? r0 : pk_[0];
    f0.u[1] = hi ? r1 : pk_[1];
    f0.u[2] = hi ? pk_[2] : r0;
    f0.u[3] = hi ? pk_[3] : r1;
    f1.u[0] = hi ? r2 : pk_[4];
    f1.u[1] = hi ? r3 : pk_[5];
    f1.u[2] = hi ? pk_[6] : r2;
    f1.u[3] = hi ? pk_[7] : r3;

#pragma unroll
    for (int d = 0; d < 3; ++d) {
      const short* Vr = Vb + (((long)t * 3 + d) * 2 * 64) * 8;
      short8 vf0 = *(const short8*)(Vr + l * 8);
      ctxv[d] = __builtin_amdgcn_mfma_f32_32x32x16_bf16(vf0, f0.s8, ctxv[d], 0, 0, 0);
      short8 vf1 = *(const short8*)(Vr + (64 + l) * 8);
      ctxv[d] = __builtin_amdgcn_mfma_f32_32x32x16_bf16(vf1, f1.s8, ctxv[d], 0, 0, 0);
    }
  }

  float invl = 1.f / l_;
  if (s <= SEQ - 1) {
    short* Cr = CTX + (long)(b * SEQ + s) * HDIM + h * DH;
#pragma unroll
    for (int d = 0; d < 3; ++d)
#pragma unroll
      for (int g = 0; g < 4; ++g) {
        short4_ o;
#pragma unroll
        for (int r = 0; r < 4; ++r) o[r] = f2bf(ctxv[d][4 * g + r] * invl);
        *(short4_*)(Cr + d * 32 + 8 * g + 4 * hi) = o;
      }
  }
}

extern "C" void kernel_launch(void* const* d_in, const int* in_sizes, int n_in,
                              void* d_out, int out_size, void* d_ws, size_t ws_size,
                              hipStream_t stream) {
  const float* hs = (const float*)d_in[0];
  const float* Wq = (const float*)d_in[1];
  const float* bq = (const float*)d_in[2];
  const float* Wk = (const float*)d_in[3];
  const float* bk = (const float*)d_in[4];
  const float* Wv = (const float*)d_in[5];
  const float* bv = (const float*)d_in[6];
  const float* Wo = (const float*)d_in[7];
  const float* bo = (const float*)d_in[8];
  const int* rows = (const int*)d_in[9];
  const int* cols = (const int*)d_in[10];
  float* out = (float*)d_out;

  char* ws = (char*)d_ws;
  short* X   = (short*)(ws);               // 8200*1152*2      = 18,892,800
  short* Wt  = (short*)(ws + 18892800);    // 3456*1152*2      =  7,962,624
  short* Wot = (short*)(ws + 26855424);    // 1152*1152*2      =  2,654,208
  short* QKV = (short*)(ws + 29509632);    // 8200*3456*2      = 56,678,400
  short* Vf  = (short*)(ws + 86188032);    // 96*33*6*64*16B   = 19,464,192
  short* CTX = (short*)(ws + 105652224);   // 8200*1152*2      = 18,892,800  (end 124,545,024)
  short* Kf  = (short*)(ws);               // 19,464,192 — reuses X+Wt region (dead after gemm<0>)

  convx<<<9225, 256, 0, stream>>>(hs, X);
  convw_t<<<dim3(18, 18, 3), 256, 0, stream>>>(Wq, Wk, Wv, Wt);
  convw_t<<<dim3(18, 18, 1), 256, 0, stream>>>(Wo, Wo, Wo, Wot);
  gemm256<0><<<462, 512, 0, stream>>>(X, Wt, bq, bk, bv, QKV, N_QKV, 33);   // 33 M x 14 N tiles
  rotary_q<<<1538, 256, 0, stream>>>(QKV, rows, cols);
  fragpack<<<dim3(33, 96), 256, 0, stream>>>(QKV, Kf, Vf, rows, cols);
  attn_kernel<<<1632, 128, 0, stream>>>(QKV, Kf, Vf, CTX);
  gemm256<1><<<165, 512, 0, stream>>>(CTX, Wot, bo, bo, bo, out, HDIM, 33); // 33 M x 5 N tiles
}